// Round 4
// baseline (3029.740 us; speedup 1.0000x reference)
//
#include <hip/hip_runtime.h>

typedef __attribute__((ext_vector_type(8))) short short8;
typedef __attribute__((ext_vector_type(4))) float f32x4;
typedef __attribute__((ext_vector_type(4))) unsigned short ushort4v;

#define AS1(p) ((const __attribute__((address_space(1))) void*)(p))
#define AS3(p) ((__attribute__((address_space(3))) void*)(p))

__device__ __forceinline__ float bf2f(unsigned short v) {
    union { unsigned u; float f; } c; c.u = ((unsigned)v) << 16; return c.f;
}
__device__ __forceinline__ unsigned short f2bf(float f) {
    union { float f; unsigned u; } c; c.f = f;
    unsigned u = c.u;
    return (unsigned short)((u + 0x7FFFu + ((u >> 16) & 1u)) >> 16);
}

// ---------------------------------------------------------------------------
// fp32 [R][C] -> bf16 [C][R] transpose+convert (weights)
// ---------------------------------------------------------------------------
__global__ __launch_bounds__(256) void transpose_cvt(
    const float* __restrict__ in, unsigned short* __restrict__ out, int R, int C)
{
    __shared__ float tile[32][33];
    int bx = blockIdx.x * 32;            // C dim
    int by = blockIdx.y * 32;            // R dim
    int tx = threadIdx.x & 31, ty = threadIdx.x >> 5;   // 32 x 8
    #pragma unroll
    for (int i = ty; i < 32; i += 8)
        tile[i][tx] = in[(size_t)(by + i) * C + bx + tx];
    __syncthreads();
    #pragma unroll
    for (int i = ty; i < 32; i += 8)
        out[(size_t)(bx + i) * R + by + tx] = f2bf(tile[tx][i]);
}

// ---------------------------------------------------------------------------
__global__ __launch_bounds__(256) void cvt_f32_bf16(
    const float* __restrict__ in, unsigned short* __restrict__ out, int n)
{
    int i4 = (blockIdx.x * 256 + threadIdx.x) * 4;
    if (i4 < n) {
        f32x4 v = *(const f32x4*)(in + i4);
        ushort4v o = { f2bf(v[0]), f2bf(v[1]), f2bf(v[2]), f2bf(v[3]) };
        *(ushort4v*)(out + i4) = o;
    }
}

// ---------------------------------------------------------------------------
// bf16 per-bh transpose: in [64 bh][1024 s][64 d] -> out [64 bh][64 d][1024 s]
// ---------------------------------------------------------------------------
__global__ __launch_bounds__(256) void transpose_v(
    const unsigned short* __restrict__ in, unsigned short* __restrict__ out)
{
    __shared__ unsigned short t[64][66];
    int bh = blockIdx.y, s0 = blockIdx.x * 64;
    int tid = threadIdx.x;
    int r = tid >> 2, c = (tid & 3) * 16;
    const unsigned short* ip = in + ((size_t)bh * 1024 + s0 + r) * 64 + c;
    short8 a0 = *(const short8*)ip;
    short8 a1 = *(const short8*)(ip + 8);
    #pragma unroll
    for (int i = 0; i < 8; i++) t[r][c + i] = (unsigned short)a0[i];
    #pragma unroll
    for (int i = 0; i < 8; i++) t[r][c + 8 + i] = (unsigned short)a1[i];
    __syncthreads();
    int d = tid >> 2, sc = (tid & 3) * 16;
    short8 v0, v1;
    #pragma unroll
    for (int i = 0; i < 8; i++) v0[i] = (short)t[sc + i][d];
    #pragma unroll
    for (int i = 0; i < 8; i++) v1[i] = (short)t[sc + 8 + i][d];
    unsigned short* op = out + ((size_t)bh * 64 + d) * 1024 + s0 + sc;
    *(short8*)op = v0;
    *(short8*)(op + 8) = v1;
}

// ---------------------------------------------------------------------------
// 128x128 GEMM, 2-phase double-buffered (T3 minimum form):
//   prologue: STAGE(buf0, t=0); barrier;
//   iter t:   STAGE(buf^1, t+1)  [loads in flight]  -> ds_read+MFMA(buf)
//             -> ONE barrier (its vmcnt(0) lands after compute, not before).
// MODE 0: fp32 out (split-K: blockIdx.z selects K-chunk + partial buffer;
//         bias added only by z==0). MODE 1: bf16 relu(x+bias0). MODE 2: qkv scatter.
// ---------------------------------------------------------------------------
template <int MODE>
__global__ __launch_bounds__(256)
void gemm_bt(const unsigned short* __restrict__ A,
             const unsigned short* __restrict__ Bt,
             const float* __restrict__ bias0,
             const float* __restrict__ bias1,
             const float* __restrict__ bias2,
             float* __restrict__ outF0,
             float* __restrict__ outF1,
             float* __restrict__ outF2,
             float* __restrict__ outF3,
             unsigned short* __restrict__ outB,
             int M, int N, int K, int Kc)
{
    __shared__ __align__(16) unsigned short As[2][128 * 32];   // [m][k]
    __shared__ __align__(16) unsigned short Bs[2][128 * 32];   // [n][k]

    int tid = threadIdx.x;
    int wave = tid >> 6, lane = tid & 63;
    int ml = lane & 15, quad = lane >> 4;
    int m0 = blockIdx.y * 128, n0 = blockIdx.x * 128;
    int z = blockIdx.z;
    int wm = (wave >> 1) * 64, wn = (wave & 1) * 64;

    f32x4 acc[4][4];
    #pragma unroll
    for (int i = 0; i < 4; i++)
        #pragma unroll
        for (int j = 0; j < 4; j++)
            #pragma unroll
            for (int r = 0; r < 4; r++) acc[i][j][r] = 0.0f;

    int srow = lane >> 2, skp = (lane & 3) * 8;
    int kbeg = z * Kc;
    int nt = Kc >> 5;

    auto stage = [&](int buf, int k0) {
        #pragma unroll
        for (int c2 = 0; c2 < 2; c2++) {
            int c = wave + c2 * 4;
            const unsigned short* ga = A + (size_t)(m0 + c * 16 + srow) * K + (k0 + skp);
            __builtin_amdgcn_global_load_lds(AS1(ga), AS3(&As[buf][c * 512]), 16, 0, 0);
            const unsigned short* gb = Bt + (size_t)(n0 + c * 16 + srow) * K + (k0 + skp);
            __builtin_amdgcn_global_load_lds(AS1(gb), AS3(&Bs[buf][c * 512]), 16, 0, 0);
        }
    };

    stage(0, kbeg);
    __syncthreads();

    for (int t = 0; t < nt; t++) {
        int cur = t & 1;
        if (t + 1 < nt) stage(cur ^ 1, kbeg + (t + 1) * 32);

        short8 af[4], bfr[4];
        #pragma unroll
        for (int i = 0; i < 4; i++)
            af[i] = *(const short8*)(&As[cur][(wm + i * 16 + ml) * 32 + quad * 8]);
        #pragma unroll
        for (int j = 0; j < 4; j++)
            bfr[j] = *(const short8*)(&Bs[cur][(wn + j * 16 + ml) * 32 + quad * 8]);
        #pragma unroll
        for (int i = 0; i < 4; i++)
            #pragma unroll
            for (int j = 0; j < 4; j++)
                acc[i][j] = __builtin_amdgcn_mfma_f32_16x16x32_bf16(af[i], bfr[j], acc[i][j], 0, 0, 0);

        if (t + 1 < nt) __syncthreads();
    }

    float* outF = (z == 0) ? outF0 : (z == 1) ? outF1 : (z == 2) ? outF2 : outF3;

    size_t Ns = (size_t)N;
    #pragma unroll
    for (int j = 0; j < 4; j++) {
        int ng = n0 + wn + j * 16 + ml;
        float bv;
        if (MODE == 2) {
            int which = ng >> 10;
            const float* bp = (which == 0) ? bias0 : ((which == 1) ? bias1 : bias2);
            bv = bp[ng & 1023];
        } else {
            bv = (z == 0) ? bias0[ng] : 0.0f;
        }
        #pragma unroll
        for (int i = 0; i < 4; i++) {
            #pragma unroll
            for (int r = 0; r < 4; r++) {
                int mg = m0 + wm + i * 16 + quad * 4 + r;
                float v = acc[i][j][r] + bv;
                if (MODE == 0) {
                    outF[(size_t)mg * Ns + ng] = v;
                } else if (MODE == 1) {
                    outB[(size_t)mg * Ns + ng] = f2bf(fmaxf(v, 0.0f));
                } else {
                    int which = ng >> 10, wi = ng & 1023;
                    int h = wi >> 6, d = wi & 63;
                    int b = mg >> 10, s = mg & 1023;
                    outB[(size_t)which * 4194304 +
                         ((size_t)(b * 16 + h) * 1024 + s) * 64 + d] = f2bf(v);
                }
            }
        }
    }
}

// ---------------------------------------------------------------------------
// qEc[b,h,s,n] = ( q[b,h,s,:] . Erel[n,:] + Brel[h,n] ) * scale
// ---------------------------------------------------------------------------
__global__ __launch_bounds__(256) void qe_kernel(
    const unsigned short* __restrict__ q,     // [B,H,S,64] bf16
    const float* __restrict__ Erel,           // [33][64]
    const float* __restrict__ Brel,           // [16][33]
    float* __restrict__ out)                  // [B,H,S,33]
{
    int idx = blockIdx.x * 256 + threadIdx.x;
    if (idx >= 2162688) return;
    int n = idx % 33;
    int row = idx / 33;
    const short8* qv = (const short8*)(q + (size_t)row * 64);
    float s = 0.0f;
    #pragma unroll
    for (int c = 0; c < 8; c++) {
        short8 qq = qv[c];
        const float* e = Erel + n * 64 + c * 8;
        #pragma unroll
        for (int j = 0; j < 8; j++) s += bf2f((unsigned short)qq[j]) * e[j];
    }
    int h = (row >> 10) & 15;
    out[idx] = (s + Brel[h * 33 + n]) * 0.125f;
}

// ---------------------------------------------------------------------------
// Flash attention, barrier-free: K and V^T fragments read DIRECTLY from
// global (L2-resident: 8 bh/XCD x 256KB + shared rid slice < 4MB L2, thanks
// to qt-slow block swizzle). No K/V LDS staging -> zero __syncthreads in the
// k-loop -> no vmcnt(0) drains; V-frag + rid loads issue at tile top and
// hide under QK^T+softmax. Ps/combS are per-wave LDS (lgkm-ordered only).
// T5 setprio around MFMA clusters; T13 defer-max (THR=8).
// launch_bounds (256,3): ~168 VGPR budget, no spill risk (est. use ~130).
// ---------------------------------------------------------------------------
__global__ __launch_bounds__(256, 3)
void attn_kernel(const unsigned short* __restrict__ Q,   // [B,H,S,64]
                 const unsigned short* __restrict__ Kin, // [B,H,S,64]
                 const unsigned short* __restrict__ Vt,  // [B,H,64,S]
                 const int* __restrict__ rid,            // [S,S]
                 const float* __restrict__ qEc,          // [B,H,S,33] prescaled incl Brel
                 unsigned short* __restrict__ outp)      // [B,S,H*64]
{
    const float scale = 0.125f;
    int bid = blockIdx.x;
    int bh = bid & 63, qt = bid >> 6;
    int b = bh >> 4, h = bh & 15;
    int q0 = qt * 64;
    size_t bhs = (size_t)bh;

    __shared__ __align__(16) unsigned short Ps[4][16 * 72];
    __shared__ float combS[4][528];

    int tid = threadIdx.x;
    int wave = tid >> 6, lane = tid & 63;
    int ml = lane & 15, quad = lane >> 4;

    const unsigned short* Qp = Q + (bhs * 1024 + q0) * 64;
    const unsigned short* Kp = Kin + bhs * 65536;
    const unsigned short* Vp = Vt + bhs * 65536;

    // Q fragments (A layout), per-wave 16-row strip, loaded once
    short8 aq0 = *(const short8*)(Qp + (size_t)(wave * 16 + ml) * 64 + quad * 8);
    short8 aq1 = *(const short8*)(Qp + (size_t)(wave * 16 + ml) * 64 + 32 + quad * 8);

    // comb strip: rows [q0+wave*16, +16), 33 floats each, contiguous
    {
        const float* qEw = qEc + (bhs * 1024 + q0 + wave * 16) * 33;
        for (int i = lane; i < 528; i += 64) combS[wave][i] = qEw[i];
    }

    // rid gather rows for this lane: q = q0 + wave*16 + quad*4 + r
    const int* ridBase = rid + (size_t)(q0 + wave * 16 + quad * 4) * 1024;

    // per-lane fragment bases (direct global reads, L2-hot)
    const unsigned short* Kb = Kp + (size_t)ml * 64 + quad * 8;     // + (kt*64 + j*16)*64
    const unsigned short* Vb = Vp + (size_t)ml * 1024 + quad * 8;   // + j*16*1024 + kt*64

    float m_st[4], l_st[4];
    f32x4 o_acc[4];
    #pragma unroll
    for (int r = 0; r < 4; r++) { m_st[r] = -1e30f; l_st[r] = 0.0f; }
    #pragma unroll
    for (int j = 0; j < 4; j++)
        #pragma unroll
        for (int r = 0; r < 4; r++) o_acc[j][r] = 0.0f;

    for (int kt = 0; kt < 16; kt++) {
        // V fragments for this tile: issue first, consumed after softmax
        short8 bv0[4], bv1[4];
        #pragma unroll
        for (int j = 0; j < 4; j++) {
            const unsigned short* vp = Vb + (size_t)j * 16384 + kt * 64;
            bv0[j] = *(const short8*)(vp);
            bv1[j] = *(const short8*)(vp + 32);
        }
        // rel-id gather: issued here, consumed in softmax (hides under QK^T)
        int rv[4][4];
        #pragma unroll
        for (int r = 0; r < 4; r++) {
            const int* rp = ridBase + (size_t)r * 1024 + kt * 64 + ml;
            #pragma unroll
            for (int j = 0; j < 4; j++) rv[r][j] = rp[j * 16];
        }

        // QK^T, K fragments direct from global
        f32x4 s_acc[4];
        #pragma unroll
        for (int j = 0; j < 4; j++)
            #pragma unroll
            for (int r = 0; r < 4; r++) s_acc[j][r] = 0.0f;
        __builtin_amdgcn_s_setprio(1);
        #pragma unroll
        for (int j = 0; j < 4; j++) {
            const unsigned short* kp = Kb + (size_t)(kt * 64 + j * 16) * 64;
            short8 bk0 = *(const short8*)(kp);
            short8 bk1 = *(const short8*)(kp + 32);
            s_acc[j] = __builtin_amdgcn_mfma_f32_16x16x32_bf16(aq0, bk0, s_acc[j], 0, 0, 0);
            s_acc[j] = __builtin_amdgcn_mfma_f32_16x16x32_bf16(aq1, bk1, s_acc[j], 0, 0, 0);
        }
        __builtin_amdgcn_s_setprio(0);

        // rel score add + row-max
        float mx[4];
        #pragma unroll
        for (int r = 0; r < 4; r++) {
            int rl = quad * 4 + r;
            #pragma unroll
            for (int j = 0; j < 4; j++)
                s_acc[j][r] = s_acc[j][r] * scale + combS[wave][rl * 33 + rv[r][j]];
            float m0 = fmaxf(fmaxf(s_acc[0][r], s_acc[1][r]), fmaxf(s_acc[2][r], s_acc[3][r]));
            m0 = fmaxf(m0, __shfl_xor(m0, 1, 64));
            m0 = fmaxf(m0, __shfl_xor(m0, 2, 64));
            m0 = fmaxf(m0, __shfl_xor(m0, 4, 64));
            m0 = fmaxf(m0, __shfl_xor(m0, 8, 64));
            mx[r] = m0;
        }

        // T13 defer-max: skip O-rescale when max growth <= 8 for all rows
        bool ok = (mx[0] <= m_st[0] + 8.0f) & (mx[1] <= m_st[1] + 8.0f)
                & (mx[2] <= m_st[2] + 8.0f) & (mx[3] <= m_st[3] + 8.0f);
        if (__all(ok)) {
            #pragma unroll
            for (int r = 0; r < 4; r++) {
                int rl = quad * 4 + r;
                float ps = 0.0f;
                #pragma unroll
                for (int j = 0; j < 4; j++) {
                    float pv = __expf(s_acc[j][r] - m_st[r]);
                    ps += pv;
                    Ps[wave][rl * 72 + j * 16 + ml] = f2bf(pv);
                }
                ps += __shfl_xor(ps, 1, 64);
                ps += __shfl_xor(ps, 2, 64);
                ps += __shfl_xor(ps, 4, 64);
                ps += __shfl_xor(ps, 8, 64);
                l_st[r] += ps;
            }
        } else {
            #pragma unroll
            for (int r = 0; r < 4; r++) {
                int rl = quad * 4 + r;
                float mnew = fmaxf(m_st[r], mx[r]);
                float alpha = __expf(m_st[r] - mnew);
                float ps = 0.0f;
                #pragma unroll
                for (int j = 0; j < 4; j++) {
                    float pv = __expf(s_acc[j][r] - mnew);
                    ps += pv;
                    Ps[wave][rl * 72 + j * 16 + ml] = f2bf(pv);
                }
                ps += __shfl_xor(ps, 1, 64);
                ps += __shfl_xor(ps, 2, 64);
                ps += __shfl_xor(ps, 4, 64);
                ps += __shfl_xor(ps, 8, 64);
                l_st[r] = l_st[r] * alpha + ps;
                m_st[r] = mnew;
                #pragma unroll
                for (int j = 0; j < 4; j++) o_acc[j][r] *= alpha;
            }
        }

        // P.V: A from per-wave Ps (LDS roundtrip), B from prefetched V regs
        short8 ap0 = *(const short8*)(&Ps[wave][ml * 72 + quad * 8]);
        short8 ap1 = *(const short8*)(&Ps[wave][ml * 72 + 32 + quad * 8]);
        __builtin_amdgcn_s_setprio(1);
        #pragma unroll
        for (int j = 0; j < 4; j++) {
            o_acc[j] = __builtin_amdgcn_mfma_f32_16x16x32_bf16(ap0, bv0[j], o_acc[j], 0, 0, 0);
            o_acc[j] = __builtin_amdgcn_mfma_f32_16x16x32_bf16(ap1, bv1[j], o_acc[j], 0, 0, 0);
        }
        __builtin_amdgcn_s_setprio(0);
    }

    #pragma unroll
    for (int r = 0; r < 4; r++) {
        int qrow = wave * 16 + quad * 4 + r;
        float invl = 1.0f / l_st[r];
        size_t base = ((size_t)(b * 1024 + q0 + qrow)) * 1024 + h * 64;
        #pragma unroll
        for (int j = 0; j < 4; j++)
            outp[base + j * 16 + ml] = f2bf(o_acc[j][r] * invl);
    }
}

// ---------------------------------------------------------------------------
// LayerNorm( a + p0 [+ p1 [+ p2 [+ p3]]] ) * g + be  -> fp32 out (+ bf16 out).
// D = 1024. NP = number of partial buffers summed onto a.
// In-place safe: each thread reads its own 4 elements before writing them.
// ---------------------------------------------------------------------------
template <int NP>
__global__ __launch_bounds__(256) void ln_kernel(
    const float* __restrict__ a,
    const float* __restrict__ p0, const float* __restrict__ p1,
    const float* __restrict__ p2, const float* __restrict__ p3,
    const float* __restrict__ g, const float* __restrict__ be,
    float* __restrict__ outF, unsigned short* __restrict__ outB)
{
    int row = blockIdx.x, tid = threadIdx.x;
    int wave = tid >> 6, lane = tid & 63;
    size_t off = (size_t)row * 1024 + tid * 4;
    f32x4 x = *(const f32x4*)(a + off);
    {
        f32x4 t = *(const f32x4*)(p0 + off);
        #pragma unroll
        for (int i = 0; i < 4; i++) x[i] += t[i];
    }
    if (NP > 1) {
        f32x4 t = *(const f32x4*)(p1 + off);
        #pragma unroll
        for (int i = 0; i < 4; i++) x[i] += t[i];
    }
    if (NP > 2) {
        f32x4 t = *(const f32x4*)(p2 + off);
        #pragma unroll
        for (int i = 0; i < 4; i++) x[i] += t[i];
    }
    if (NP > 3) {
        f32x4 t = *(const f32x4*)(p3 + off);
        #pragma unroll
        for (int i = 0; i < 4; i++) x[i] += t[i];
    }
    float s1 = x[0] + x[1] + x[2] + x[3];
    float s2 = x[0]*x[0] + x[1]*x[1] + x[2]*x[2] + x[3]*x[3];
    #pragma unroll
    for (int offx = 1; offx < 64; offx <<= 1) {
        s1 += __shfl_xor(s1, offx, 64);
        s2 += __shfl_xor(s2, offx, 64);
    }
    __shared__ float r1[4], r2[4];
    if (lane == 0) { r1[wave] = s1; r2[wave] = s2; }
    __syncthreads();
    s1 = r1[0] + r1[1] + r1[2] + r1[3];
    s2 = r2[0] + r2[1] + r2[2] + r2[3];
    float mean = s1 * (1.0f / 1024.0f);
    float var  = s2 * (1.0f / 1024.0f) - mean * mean;
    float inv  = rsqrtf(var + 1e-6f);
    f32x4 gg = *(const f32x4*)(g + tid * 4);
    f32x4 bb = *(const f32x4*)(be + tid * 4);
    f32x4 o;
    #pragma unroll
    for (int i = 0; i < 4; i++) o[i] = (x[i] - mean) * inv * gg[i] + bb[i];
    *(f32x4*)(outF + off) = o;
    if (outB != nullptr) {
        ushort4v ov = { f2bf(o[0]), f2bf(o[1]), f2bf(o[2]), f2bf(o[3]) };
        *(ushort4v*)(outB + off) = ov;
    }
}

// ---------------------------------------------------------------------------
extern "C" void kernel_launch(void* const* d_in, const int* in_sizes, int n_in,
                              void* d_out, int out_size, void* d_ws, size_t ws_size,
                              hipStream_t stream)
{
    const float* x_in = (const float*)d_in[0];
    const int*   rid  = (const int*)d_in[1];
    const float* Wq = (const float*)d_in[2];  const float* bq = (const float*)d_in[3];
    const float* Wk = (const float*)d_in[4];  const float* bk = (const float*)d_in[5];
    const float* Wv = (const float*)d_in[6];  const float* bv = (const float*)d_in[7];
    const float* Wo = (const float*)d_in[8];  const float* bo = (const float*)d_in[9];
    const float* Erel = (const float*)d_in[10];
    const float* Brel = (const float*)d_in[11];
    const float* g1 = (const float*)d_in[12]; const float* be1 = (const float*)d_in[13];
    const float* g2 = (const float*)d_in[14]; const float* be2 = (const float*)d_in[15];
    const float* W1 = (const float*)d_in[16]; const float* b1 = (const float*)d_in[17];
    const float* W2 = (const float*)d_in[18]; const float* b2 = (const float*)d_in[19];

    char* p = (char*)d_ws;
    auto alloc = [&](size_t bytes) {
        char* r = p; p += (bytes + 255) & ~(size_t)255; return (void*)r;
    };
    unsigned short* wqkv_t = (unsigned short*)alloc(3ull * 1024 * 1024 * 2); // [3072][1024]
    unsigned short* wo_t   = (unsigned short*)alloc(1024ull * 1024 * 2);
    unsigned short* w1_t   = (unsigned short*)alloc(4096ull * 1024 * 2);
    unsigned short* w2_t   = (unsigned short*)alloc(1024ull * 4096 * 2);
    float*          xf     = (float*)alloc(4096ull * 1024 * 4);
    unsigned short* xb     = (unsigned short*)alloc(4096ull * 1024 * 2);
    unsigned short* qkvb   = (unsigned short*)alloc(3ull * 4194304 * 2);     // q|k|v
    unsigned short* vtb    = (unsigned short*)alloc(4194304ull * 2);         // V^T [B,H,64,S]
    unsigned short* attnb  = (unsigned short*)alloc(4096ull * 1024 * 2);
    float*          qEcb   = (float*)alloc(2162688ull * 4);                  // [B,H,S,33]
    float*          proj   = (float*)alloc(4096ull * 1024 * 4);
    float*          ffin   = (float*)alloc(4096ull * 1024 * 4);
    unsigned short* ffinb  = (unsigned short*)alloc(4096ull * 1024 * 2);
    unsigned short* hb     = qkvb;   // 32MB reuse (qkvb dead by FFN1; spans into vtb)

    // Split-K partial buffers, all reusing dead regions at their point of use:
    //  O-proj (z=2):  P0 = proj, P1 = ffin            (ffin dead until LN1 writes it)
    //  FFN2   (z=4):  P0 = proj, P1 = xf              (residual already consumed by LN1)
    //                 P2 = attnb∪qEcb (17.0 MB contig, both consumed)
    //                 P3 = wqkv_t∪wo_t∪w1_t (exactly 16.78 MB contig, weights consumed;
    //                      rewritten only at next layer's transpose, after LN2)
    float* pP2 = (float*)attnb;
    float* pP3 = (float*)wqkv_t;

    cvt_f32_bf16<<<4096, 256, 0, stream>>>(x_in, xb, 4194304);

    const float* xcur = x_in;
    for (int l = 0; l < 6; l++) {
        transpose_cvt<<<dim3(32, 32), 256, 0, stream>>>(Wq + (size_t)l * 1048576, wqkv_t,           1024, 1024);
        transpose_cvt<<<dim3(32, 32), 256, 0, stream>>>(Wk + (size_t)l * 1048576, wqkv_t + 1048576, 1024, 1024);
        transpose_cvt<<<dim3(32, 32), 256, 0, stream>>>(Wv + (size_t)l * 1048576, wqkv_t + 2097152, 1024, 1024);
        transpose_cvt<<<dim3(32, 32), 256, 0, stream>>>(Wo + (size_t)l * 1048576, wo_t,             1024, 1024);
        transpose_cvt<<<dim3(128, 32), 256, 0, stream>>>(W1 + (size_t)l * 4194304, w1_t, 1024, 4096);
        transpose_cvt<<<dim3(32, 128), 256, 0, stream>>>(W2 + (size_t)l * 4194304, w2_t, 4096, 1024);

        // QKV fused: [4096,1024] @ [1024,3072] -> q,k,v [B,H,S,64]
        gemm_bt<2><<<dim3(24, 32, 1), 256, 0, stream>>>(
            xb, wqkv_t, bq + l * 1024, bk + l * 1024, bv + l * 1024,
            nullptr, nullptr, nullptr, nullptr, qkvb, 4096, 3072, 1024, 1024);

        transpose_v<<<dim3(16, 64), 256, 0, stream>>>(qkvb + 8388608, vtb);

        qe_kernel<<<8448, 256, 0, stream>>>(qkvb, Erel + l * 2112, Brel + l * 528, qEcb);

        attn_kernel<<<1024, 256, 0, stream>>>(
            qkvb, qkvb + 4194304, vtb, rid, qEcb, attnb);

        // O projection, split-K x2 -> partials proj, ffin
        gemm_bt<0><<<dim3(8, 32, 2), 256, 0, stream>>>(
            attnb, wo_t, bo + l * 1024, nullptr, nullptr,
            proj, ffin, nullptr, nullptr, nullptr, 4096, 1024, 1024, 512);

        // ff_in = LN(x + proj + ffin)   (writes ffin in-place: per-thread safe)
        ln_kernel<2><<<4096, 256, 0, stream>>>(
            xcur, proj, ffin, nullptr, nullptr,
            g1 + l * 1024, be1 + l * 1024, ffin, ffinb);

        // FFN1: relu(ffin @ W1 + b1) -> bf16 hb
        gemm_bt<1><<<dim3(32, 32, 1), 256, 0, stream>>>(
            ffinb, w1_t, b1 + l * 4096, nullptr, nullptr,
            nullptr, nullptr, nullptr, nullptr, hb, 4096, 4096, 1024, 1024);

        // FFN2: hb @ W2 + b2, split-K x4 -> partials proj, xf, attnb-region, wqkv-region
        gemm_bt<0><<<dim3(8, 32, 4), 256, 0, stream>>>(
            hb, w2_t, b2 + l * 1024, nullptr, nullptr,
            proj, xf, pP2, pP3, nullptr, 4096, 1024, 4096, 1024);

        // x_next = LN(ffin + sum of 4 partials)
        float* lnout = (l == 5) ? (float*)d_out : xf;
        unsigned short* lnoutb = (l == 5) ? nullptr : xb;
        ln_kernel<4><<<4096, 256, 0, stream>>>(
            ffin, proj, xf, pP2, pP3,
            g2 + l * 1024, be2 + l * 1024, lnout, lnoutb);
        xcur = xf;
    }
}

// Round 5
// 2385.860 us; speedup vs baseline: 1.2699x; 1.2699x over previous
//
#include <hip/hip_runtime.h>

typedef __attribute__((ext_vector_type(8))) short short8;
typedef __attribute__((ext_vector_type(4))) float f32x4;
typedef __attribute__((ext_vector_type(4))) unsigned short ushort4v;

#define AS1(p) ((const __attribute__((address_space(1))) void*)(p))
#define AS3(p) ((__attribute__((address_space(3))) void*)(p))

__device__ __forceinline__ float bf2f(unsigned short v) {
    union { unsigned u; float f; } c; c.u = ((unsigned)v) << 16; return c.f;
}
__device__ __forceinline__ unsigned short f2bf(float f) {
    union { float f; unsigned u; } c; c.f = f;
    unsigned u = c.u;
    return (unsigned short)((u + 0x7FFFu + ((u >> 16) & 1u)) >> 16);
}

// ---------------------------------------------------------------------------
// fp32 [R][C] -> bf16 [C][R] transpose+convert (weights)
// ---------------------------------------------------------------------------
__global__ __launch_bounds__(256) void transpose_cvt(
    const float* __restrict__ in, unsigned short* __restrict__ out, int R, int C)
{
    __shared__ float tile[32][33];
    int bx = blockIdx.x * 32;            // C dim
    int by = blockIdx.y * 32;            // R dim
    int tx = threadIdx.x & 31, ty = threadIdx.x >> 5;   // 32 x 8
    #pragma unroll
    for (int i = ty; i < 32; i += 8)
        tile[i][tx] = in[(size_t)(by + i) * C + bx + tx];
    __syncthreads();
    #pragma unroll
    for (int i = ty; i < 32; i += 8)
        out[(size_t)(bx + i) * R + by + tx] = f2bf(tile[tx][i]);
}

// ---------------------------------------------------------------------------
__global__ __launch_bounds__(256) void cvt_f32_bf16(
    const float* __restrict__ in, unsigned short* __restrict__ out, int n)
{
    int i4 = (blockIdx.x * 256 + threadIdx.x) * 4;
    if (i4 < n) {
        f32x4 v = *(const f32x4*)(in + i4);
        ushort4v o = { f2bf(v[0]), f2bf(v[1]), f2bf(v[2]), f2bf(v[3]) };
        *(ushort4v*)(out + i4) = o;
    }
}

// ---------------------------------------------------------------------------
// bf16 per-bh transpose: in [64 bh][1024 s][64 d] -> out [64 bh][64 d][1024 s]
// ---------------------------------------------------------------------------
__global__ __launch_bounds__(256) void transpose_v(
    const unsigned short* __restrict__ in, unsigned short* __restrict__ out)
{
    __shared__ unsigned short t[64][66];
    int bh = blockIdx.y, s0 = blockIdx.x * 64;
    int tid = threadIdx.x;
    int r = tid >> 2, c = (tid & 3) * 16;
    const unsigned short* ip = in + ((size_t)bh * 1024 + s0 + r) * 64 + c;
    short8 a0 = *(const short8*)ip;
    short8 a1 = *(const short8*)(ip + 8);
    #pragma unroll
    for (int i = 0; i < 8; i++) t[r][c + i] = (unsigned short)a0[i];
    #pragma unroll
    for (int i = 0; i < 8; i++) t[r][c + 8 + i] = (unsigned short)a1[i];
    __syncthreads();
    int d = tid >> 2, sc = (tid & 3) * 16;
    short8 v0, v1;
    #pragma unroll
    for (int i = 0; i < 8; i++) v0[i] = (short)t[sc + i][d];
    #pragma unroll
    for (int i = 0; i < 8; i++) v1[i] = (short)t[sc + 8 + i][d];
    unsigned short* op = out + ((size_t)bh * 64 + d) * 1024 + s0 + sc;
    *(short8*)op = v0;
    *(short8*)(op + 8) = v1;
}

// ---------------------------------------------------------------------------
// 128x128 GEMM, 2-phase double-buffered (T3 minimum form):
//   prologue: STAGE(buf0, t=0); barrier;
//   iter t:   STAGE(buf^1, t+1)  [loads in flight]  -> ds_read+MFMA(buf)
//             -> ONE barrier (its vmcnt(0) lands after compute, not before).
// MODE 0: fp32 out (split-K: blockIdx.z selects K-chunk + partial buffer;
//         bias added only by z==0). MODE 1: bf16 relu(x+bias0). MODE 2: qkv scatter.
// ---------------------------------------------------------------------------
template <int MODE>
__global__ __launch_bounds__(256)
void gemm_bt(const unsigned short* __restrict__ A,
             const unsigned short* __restrict__ Bt,
             const float* __restrict__ bias0,
             const float* __restrict__ bias1,
             const float* __restrict__ bias2,
             float* __restrict__ outF0,
             float* __restrict__ outF1,
             float* __restrict__ outF2,
             float* __restrict__ outF3,
             unsigned short* __restrict__ outB,
             int M, int N, int K, int Kc)
{
    __shared__ __align__(16) unsigned short As[2][128 * 32];   // [m][k]
    __shared__ __align__(16) unsigned short Bs[2][128 * 32];   // [n][k]

    int tid = threadIdx.x;
    int wave = tid >> 6, lane = tid & 63;
    int ml = lane & 15, quad = lane >> 4;
    int m0 = blockIdx.y * 128, n0 = blockIdx.x * 128;
    int z = blockIdx.z;
    int wm = (wave >> 1) * 64, wn = (wave & 1) * 64;

    f32x4 acc[4][4];
    #pragma unroll
    for (int i = 0; i < 4; i++)
        #pragma unroll
        for (int j = 0; j < 4; j++)
            #pragma unroll
            for (int r = 0; r < 4; r++) acc[i][j][r] = 0.0f;

    int srow = lane >> 2, skp = (lane & 3) * 8;
    int kbeg = z * Kc;
    int nt = Kc >> 5;

    auto stage = [&](int buf, int k0) {
        #pragma unroll
        for (int c2 = 0; c2 < 2; c2++) {
            int c = wave + c2 * 4;
            const unsigned short* ga = A + (size_t)(m0 + c * 16 + srow) * K + (k0 + skp);
            __builtin_amdgcn_global_load_lds(AS1(ga), AS3(&As[buf][c * 512]), 16, 0, 0);
            const unsigned short* gb = Bt + (size_t)(n0 + c * 16 + srow) * K + (k0 + skp);
            __builtin_amdgcn_global_load_lds(AS1(gb), AS3(&Bs[buf][c * 512]), 16, 0, 0);
        }
    };

    stage(0, kbeg);
    __syncthreads();

    for (int t = 0; t < nt; t++) {
        int cur = t & 1;
        if (t + 1 < nt) stage(cur ^ 1, kbeg + (t + 1) * 32);

        short8 af[4], bfr[4];
        #pragma unroll
        for (int i = 0; i < 4; i++)
            af[i] = *(const short8*)(&As[cur][(wm + i * 16 + ml) * 32 + quad * 8]);
        #pragma unroll
        for (int j = 0; j < 4; j++)
            bfr[j] = *(const short8*)(&Bs[cur][(wn + j * 16 + ml) * 32 + quad * 8]);
        #pragma unroll
        for (int i = 0; i < 4; i++)
            #pragma unroll
            for (int j = 0; j < 4; j++)
                acc[i][j] = __builtin_amdgcn_mfma_f32_16x16x32_bf16(af[i], bfr[j], acc[i][j], 0, 0, 0);

        if (t + 1 < nt) __syncthreads();
    }

    float* outF = (z == 0) ? outF0 : (z == 1) ? outF1 : (z == 2) ? outF2 : outF3;

    size_t Ns = (size_t)N;
    #pragma unroll
    for (int j = 0; j < 4; j++) {
        int ng = n0 + wn + j * 16 + ml;
        float bv;
        if (MODE == 2) {
            int which = ng >> 10;
            const float* bp = (which == 0) ? bias0 : ((which == 1) ? bias1 : bias2);
            bv = bp[ng & 1023];
        } else {
            bv = (z == 0) ? bias0[ng] : 0.0f;
        }
        #pragma unroll
        for (int i = 0; i < 4; i++) {
            #pragma unroll
            for (int r = 0; r < 4; r++) {
                int mg = m0 + wm + i * 16 + quad * 4 + r;
                float v = acc[i][j][r] + bv;
                if (MODE == 0) {
                    outF[(size_t)mg * Ns + ng] = v;
                } else if (MODE == 1) {
                    outB[(size_t)mg * Ns + ng] = f2bf(fmaxf(v, 0.0f));
                } else {
                    int which = ng >> 10, wi = ng & 1023;
                    int h = wi >> 6, d = wi & 63;
                    int b = mg >> 10, s = mg & 1023;
                    outB[(size_t)which * 4194304 +
                         ((size_t)(b * 16 + h) * 1024 + s) * 64 + d] = f2bf(v);
                }
            }
        }
    }
}

// ---------------------------------------------------------------------------
// qEc[b,h,s,n] = ( q[b,h,s,:] . Erel[n,:] + Brel[h,n] ) * scale
// ---------------------------------------------------------------------------
__global__ __launch_bounds__(256) void qe_kernel(
    const unsigned short* __restrict__ q,     // [B,H,S,64] bf16
    const float* __restrict__ Erel,           // [33][64]
    const float* __restrict__ Brel,           // [16][33]
    float* __restrict__ out)                  // [B,H,S,33]
{
    int idx = blockIdx.x * 256 + threadIdx.x;
    if (idx >= 2162688) return;
    int n = idx % 33;
    int row = idx / 33;
    const short8* qv = (const short8*)(q + (size_t)row * 64);
    float s = 0.0f;
    #pragma unroll
    for (int c = 0; c < 8; c++) {
        short8 qq = qv[c];
        const float* e = Erel + n * 64 + c * 8;
        #pragma unroll
        for (int j = 0; j < 8; j++) s += bf2f((unsigned short)qq[j]) * e[j];
    }
    int h = (row >> 10) & 15;
    out[idx] = (s + Brel[h * 33 + n]) * 0.125f;
}

// ---------------------------------------------------------------------------
// Flash attention (R2 structure: LDS-staged K/V, register prefetch, 2
// barriers/tile) + softmax de-serialization:
//  - T13 defer-max with LANE-LOCAL check: __all(local_max <= m+8) ==
//    (row_max <= m+8), so the common path has ZERO shuffles and skips the
//    O-rescale pass. P <= e^8; P/l is scale-invariant so bf16 precision
//    is unchanged.
//  - lane-local l accumulation: per-lane partials, row-uniform alpha at
//    rare rescale events, single cross-lane reduce in epilogue (removes
//    per-tile sum shuffles).
//  - rid gather hoisted above QK^T (latency hides under LDS reads+MFMA).
//  - T5 setprio around MFMA clusters.
// ---------------------------------------------------------------------------
__global__ __launch_bounds__(256, 3)
void attn_kernel(const unsigned short* __restrict__ Q,   // [B,H,S,64]
                 const unsigned short* __restrict__ Kin, // [B,H,S,64]
                 const unsigned short* __restrict__ Vt,  // [B,H,64,S]
                 const int* __restrict__ rid,            // [S,S]
                 const float* __restrict__ qEc,          // [B,H,S,33] prescaled incl Brel
                 unsigned short* __restrict__ outp)      // [B,S,H*64]
{
    const float scale = 0.125f;
    int bid = blockIdx.x;
    int bh = bid & 63, qt = bid >> 6;
    int b = bh >> 4, h = bh & 15;
    int q0 = qt * 64;
    size_t bhs = (size_t)bh;

    __shared__ __align__(16) unsigned short Ks[64 * 72];
    __shared__ __align__(16) unsigned short VT[64 * 72];
    __shared__ __align__(16) unsigned short Ps[4][16 * 72];
    __shared__ float combS[4][528];

    int tid = threadIdx.x;
    int wave = tid >> 6, lane = tid & 63;
    int ml = lane & 15, quad = lane >> 4;

    const unsigned short* Qp = Q + (bhs * 1024 + q0) * 64;
    const unsigned short* Kp = Kin + bhs * 65536;
    const unsigned short* Vp = Vt + bhs * 65536;

    // Q fragments (A layout), per-wave 16-row strip, loaded once
    short8 aq0 = *(const short8*)(Qp + (size_t)(wave * 16 + ml) * 64 + quad * 8);
    short8 aq1 = *(const short8*)(Qp + (size_t)(wave * 16 + ml) * 64 + 32 + quad * 8);

    // comb strip: rows [q0+wave*16, +16), 33 floats each, contiguous
    {
        const float* qEw = qEc + (bhs * 1024 + q0 + wave * 16) * 33;
        for (int i = lane; i < 528; i += 64) combS[wave][i] = qEw[i];
    }

    // staging coords: 64 rows x 64 cols, thread -> (row, 16-col chunk)
    int srow = tid >> 2, scol = (tid & 3) * 16;
    const unsigned short* Kg = Kp + (size_t)srow * 64 + scol;        // +kt*64*64
    const unsigned short* Vg = Vp + (size_t)srow * 1024 + scol;      // +kt*64
    // rid gather rows for this lane: q = q0 + wave*16 + quad*4 + r
    const int* ridBase = rid + (size_t)(q0 + wave * 16 + quad * 4) * 1024;

    float m_st[4], l_st[4];
    f32x4 o_acc[4];
    #pragma unroll
    for (int r = 0; r < 4; r++) { m_st[r] = -1e30f; l_st[r] = 0.0f; }
    #pragma unroll
    for (int j = 0; j < 4; j++)
        #pragma unroll
        for (int r = 0; r < 4; r++) o_acc[j][r] = 0.0f;

    // prefetch tile 0
    short8 pk0 = *(const short8*)(Kg);
    short8 pk1 = *(const short8*)(Kg + 8);
    short8 pv0 = *(const short8*)(Vg);
    short8 pv1 = *(const short8*)(Vg + 8);

    for (int kt = 0; kt < 16; kt++) {
        if (kt > 0) __syncthreads();            // prev compute done before overwrite
        *(short8*)(Ks + srow * 72 + scol)     = pk0;
        *(short8*)(Ks + srow * 72 + scol + 8) = pk1;
        *(short8*)(VT + srow * 72 + scol)     = pv0;
        *(short8*)(VT + srow * 72 + scol + 8) = pv1;
        __syncthreads();

        if (kt + 1 < 16) {                      // prefetch next tile (in flight over compute)
            pk0 = *(const short8*)(Kg + (kt + 1) * 4096);
            pk1 = *(const short8*)(Kg + (kt + 1) * 4096 + 8);
            pv0 = *(const short8*)(Vg + (kt + 1) * 64);
            pv1 = *(const short8*)(Vg + (kt + 1) * 64 + 8);
        }

        // rid gather: issue before QK^T so L2 latency hides under MFMA
        int rv[4][4];
        #pragma unroll
        for (int r = 0; r < 4; r++) {
            const int* rp = ridBase + (size_t)r * 1024 + kt * 64 + ml;
            #pragma unroll
            for (int j = 0; j < 4; j++) rv[r][j] = rp[j * 16];
        }

        // QK^T
        f32x4 s_acc[4];
        #pragma unroll
        for (int j = 0; j < 4; j++)
            #pragma unroll
            for (int r = 0; r < 4; r++) s_acc[j][r] = 0.0f;
        __builtin_amdgcn_s_setprio(1);
        #pragma unroll
        for (int j = 0; j < 4; j++) {
            short8 bk0 = *(const short8*)(Ks + (j * 16 + ml) * 72 + quad * 8);
            short8 bk1 = *(const short8*)(Ks + (j * 16 + ml) * 72 + 32 + quad * 8);
            s_acc[j] = __builtin_amdgcn_mfma_f32_16x16x32_bf16(aq0, bk0, s_acc[j], 0, 0, 0);
            s_acc[j] = __builtin_amdgcn_mfma_f32_16x16x32_bf16(aq1, bk1, s_acc[j], 0, 0, 0);
        }
        __builtin_amdgcn_s_setprio(0);

        // rel score add + LANE-LOCAL row max
        float mxl[4];
        #pragma unroll
        for (int r = 0; r < 4; r++) {
            int rl = quad * 4 + r;
            #pragma unroll
            for (int j = 0; j < 4; j++)
                s_acc[j][r] = s_acc[j][r] * scale + combS[wave][rl * 33 + rv[r][j]];
            mxl[r] = fmaxf(fmaxf(s_acc[0][r], s_acc[1][r]), fmaxf(s_acc[2][r], s_acc[3][r]));
        }

        // defer-max: all(lane_max <= m+8)  <=>  row_max <= m+8
        bool ok = (mxl[0] <= m_st[0] + 8.0f) & (mxl[1] <= m_st[1] + 8.0f)
                & (mxl[2] <= m_st[2] + 8.0f) & (mxl[3] <= m_st[3] + 8.0f);
        if (__all(ok)) {
            // common path: no shuffles, no rescale
            #pragma unroll
            for (int r = 0; r < 4; r++) {
                int rl = quad * 4 + r;
                float ps = 0.0f;
                #pragma unroll
                for (int j = 0; j < 4; j++) {
                    float pv = __expf(s_acc[j][r] - m_st[r]);
                    ps += pv;
                    Ps[wave][rl * 72 + j * 16 + ml] = f2bf(pv);
                }
                l_st[r] += ps;          // lane-local partial
            }
        } else {
            #pragma unroll
            for (int r = 0; r < 4; r++) {
                int rl = quad * 4 + r;
                float m0 = mxl[r];
                m0 = fmaxf(m0, __shfl_xor(m0, 1, 64));
                m0 = fmaxf(m0, __shfl_xor(m0, 2, 64));
                m0 = fmaxf(m0, __shfl_xor(m0, 4, 64));
                m0 = fmaxf(m0, __shfl_xor(m0, 8, 64));
                float mnew = fmaxf(m_st[r], m0);
                float alpha = __expf(m_st[r] - mnew);   // row-uniform
                float ps = 0.0f;
                #pragma unroll
                for (int j = 0; j < 4; j++) {
                    float pv = __expf(s_acc[j][r] - mnew);
                    ps += pv;
                    Ps[wave][rl * 72 + j * 16 + ml] = f2bf(pv);
                }
                l_st[r] = l_st[r] * alpha + ps;         // lane-local partial
                m_st[r] = mnew;
                #pragma unroll
                for (int j = 0; j < 4; j++) o_acc[j][r] *= alpha;
            }
        }

        // P.V: A from per-wave Ps, B from VT (both LDS)
        short8 ap0 = *(const short8*)(&Ps[wave][ml * 72 + quad * 8]);
        short8 ap1 = *(const short8*)(&Ps[wave][ml * 72 + 32 + quad * 8]);
        __builtin_amdgcn_s_setprio(1);
        #pragma unroll
        for (int j = 0; j < 4; j++) {
            short8 bv0 = *(const short8*)(VT + (j * 16 + ml) * 72 + quad * 8);
            short8 bv1 = *(const short8*)(VT + (j * 16 + ml) * 72 + 32 + quad * 8);
            o_acc[j] = __builtin_amdgcn_mfma_f32_16x16x32_bf16(ap0, bv0, o_acc[j], 0, 0, 0);
            o_acc[j] = __builtin_amdgcn_mfma_f32_16x16x32_bf16(ap1, bv1, o_acc[j], 0, 0, 0);
        }
        __builtin_amdgcn_s_setprio(0);
    }

    // epilogue: reduce lane-local l partials across the 16 lanes of each row
    #pragma unroll
    for (int r = 0; r < 4; r++) {
        float lr = l_st[r];
        lr += __shfl_xor(lr, 1, 64);
        lr += __shfl_xor(lr, 2, 64);
        lr += __shfl_xor(lr, 4, 64);
        lr += __shfl_xor(lr, 8, 64);
        int qrow = wave * 16 + quad * 4 + r;
        float invl = 1.0f / lr;
        size_t base = ((size_t)(b * 1024 + q0 + qrow)) * 1024 + h * 64;
        #pragma unroll
        for (int j = 0; j < 4; j++)
            outp[base + j * 16 + ml] = f2bf(o_acc[j][r] * invl);
    }
}

// ---------------------------------------------------------------------------
// LayerNorm( a + p0 [+ p1 [+ p2 [+ p3]]] ) * g + be  -> fp32 out (+ bf16 out).
// D = 1024. NP = number of partial buffers summed onto a.
// In-place safe: each thread reads its own 4 elements before writing them.
// ---------------------------------------------------------------------------
template <int NP>
__global__ __launch_bounds__(256) void ln_kernel(
    const float* __restrict__ a,
    const float* __restrict__ p0, const float* __restrict__ p1,
    const float* __restrict__ p2, const float* __restrict__ p3,
    const float* __restrict__ g, const float* __restrict__ be,
    float* __restrict__ outF, unsigned short* __restrict__ outB)
{
    int row = blockIdx.x, tid = threadIdx.x;
    int wave = tid >> 6, lane = tid & 63;
    size_t off = (size_t)row * 1024 + tid * 4;
    f32x4 x = *(const f32x4*)(a + off);
    {
        f32x4 t = *(const f32x4*)(p0 + off);
        #pragma unroll
        for (int i = 0; i < 4; i++) x[i] += t[i];
    }
    if (NP > 1) {
        f32x4 t = *(const f32x4*)(p1 + off);
        #pragma unroll
        for (int i = 0; i < 4; i++) x[i] += t[i];
    }
    if (NP > 2) {
        f32x4 t = *(const f32x4*)(p2 + off);
        #pragma unroll
        for (int i = 0; i < 4; i++) x[i] += t[i];
    }
    if (NP > 3) {
        f32x4 t = *(const f32x4*)(p3 + off);
        #pragma unroll
        for (int i = 0; i < 4; i++) x[i] += t[i];
    }
    float s1 = x[0] + x[1] + x[2] + x[3];
    float s2 = x[0]*x[0] + x[1]*x[1] + x[2]*x[2] + x[3]*x[3];
    #pragma unroll
    for (int offx = 1; offx < 64; offx <<= 1) {
        s1 += __shfl_xor(s1, offx, 64);
        s2 += __shfl_xor(s2, offx, 64);
    }
    __shared__ float r1[4], r2[4];
    if (lane == 0) { r1[wave] = s1; r2[wave] = s2; }
    __syncthreads();
    s1 = r1[0] + r1[1] + r1[2] + r1[3];
    s2 = r2[0] + r2[1] + r2[2] + r2[3];
    float mean = s1 * (1.0f / 1024.0f);
    float var  = s2 * (1.0f / 1024.0f) - mean * mean;
    float inv  = rsqrtf(var + 1e-6f);
    f32x4 gg = *(const f32x4*)(g + tid * 4);
    f32x4 bb = *(const f32x4*)(be + tid * 4);
    f32x4 o;
    #pragma unroll
    for (int i = 0; i < 4; i++) o[i] = (x[i] - mean) * inv * gg[i] + bb[i];
    *(f32x4*)(outF + off) = o;
    if (outB != nullptr) {
        ushort4v ov = { f2bf(o[0]), f2bf(o[1]), f2bf(o[2]), f2bf(o[3]) };
        *(ushort4v*)(outB + off) = ov;
    }
}

// ---------------------------------------------------------------------------
extern "C" void kernel_launch(void* const* d_in, const int* in_sizes, int n_in,
                              void* d_out, int out_size, void* d_ws, size_t ws_size,
                              hipStream_t stream)
{
    const float* x_in = (const float*)d_in[0];
    const int*   rid  = (const int*)d_in[1];
    const float* Wq = (const float*)d_in[2];  const float* bq = (const float*)d_in[3];
    const float* Wk = (const float*)d_in[4];  const float* bk = (const float*)d_in[5];
    const float* Wv = (const float*)d_in[6];  const float* bv = (const float*)d_in[7];
    const float* Wo = (const float*)d_in[8];  const float* bo = (const float*)d_in[9];
    const float* Erel = (const float*)d_in[10];
    const float* Brel = (const float*)d_in[11];
    const float* g1 = (const float*)d_in[12]; const float* be1 = (const float*)d_in[13];
    const float* g2 = (const float*)d_in[14]; const float* be2 = (const float*)d_in[15];
    const float* W1 = (const float*)d_in[16]; const float* b1 = (const float*)d_in[17];
    const float* W2 = (const float*)d_in[18]; const float* b2 = (const float*)d_in[19];

    char* p = (char*)d_ws;
    auto alloc = [&](size_t bytes) {
        char* r = p; p += (bytes + 255) & ~(size_t)255; return (void*)r;
    };
    unsigned short* wqkv_t = (unsigned short*)alloc(3ull * 1024 * 1024 * 2); // [3072][1024]
    unsigned short* wo_t   = (unsigned short*)alloc(1024ull * 1024 * 2);
    unsigned short* w1_t   = (unsigned short*)alloc(4096ull * 1024 * 2);
    unsigned short* w2_t   = (unsigned short*)alloc(1024ull * 4096 * 2);
    float*          xf     = (float*)alloc(4096ull * 1024 * 4);
    unsigned short* xb     = (unsigned short*)alloc(4096ull * 1024 * 2);
    unsigned short* qkvb   = (unsigned short*)alloc(3ull * 4194304 * 2);     // q|k|v
    unsigned short* vtb    = (unsigned short*)alloc(4194304ull * 2);         // V^T [B,H,64,S]
    unsigned short* attnb  = (unsigned short*)alloc(4096ull * 1024 * 2);
    float*          qEcb   = (float*)alloc(2162688ull * 4);                  // [B,H,S,33]
    float*          proj   = (float*)alloc(4096ull * 1024 * 4);
    float*          ffin   = (float*)alloc(4096ull * 1024 * 4);
    unsigned short* ffinb  = (unsigned short*)alloc(4096ull * 1024 * 2);
    unsigned short* hb     = qkvb;   // 32MB reuse (qkvb dead by FFN1; spans into vtb)

    // Split-K partial buffers, all reusing dead regions at their point of use:
    //  O-proj (z=2):  P0 = proj, P1 = ffin            (ffin dead until LN1 writes it)
    //  FFN2   (z=4):  P0 = proj, P1 = xf              (residual already consumed by LN1)
    //                 P2 = attnb∪qEcb (17.0 MB contig, both consumed)
    //                 P3 = wqkv_t∪wo_t∪w1_t (exactly 16.78 MB contig, weights consumed;
    //                      rewritten only at next layer's transpose, after LN2)
    float* pP2 = (float*)attnb;
    float* pP3 = (float*)wqkv_t;

    cvt_f32_bf16<<<4096, 256, 0, stream>>>(x_in, xb, 4194304);

    const float* xcur = x_in;
    for (int l = 0; l < 6; l++) {
        transpose_cvt<<<dim3(32, 32), 256, 0, stream>>>(Wq + (size_t)l * 1048576, wqkv_t,           1024, 1024);
        transpose_cvt<<<dim3(32, 32), 256, 0, stream>>>(Wk + (size_t)l * 1048576, wqkv_t + 1048576, 1024, 1024);
        transpose_cvt<<<dim3(32, 32), 256, 0, stream>>>(Wv + (size_t)l * 1048576, wqkv_t + 2097152, 1024, 1024);
        transpose_cvt<<<dim3(32, 32), 256, 0, stream>>>(Wo + (size_t)l * 1048576, wo_t,             1024, 1024);
        transpose_cvt<<<dim3(128, 32), 256, 0, stream>>>(W1 + (size_t)l * 4194304, w1_t, 1024, 4096);
        transpose_cvt<<<dim3(32, 128), 256, 0, stream>>>(W2 + (size_t)l * 4194304, w2_t, 4096, 1024);

        // QKV fused: [4096,1024] @ [1024,3072] -> q,k,v [B,H,S,64]
        gemm_bt<2><<<dim3(24, 32, 1), 256, 0, stream>>>(
            xb, wqkv_t, bq + l * 1024, bk + l * 1024, bv + l * 1024,
            nullptr, nullptr, nullptr, nullptr, qkvb, 4096, 3072, 1024, 1024);

        transpose_v<<<dim3(16, 64), 256, 0, stream>>>(qkvb + 8388608, vtb);

        qe_kernel<<<8448, 256, 0, stream>>>(qkvb, Erel + l * 2112, Brel + l * 528, qEcb);

        attn_kernel<<<1024, 256, 0, stream>>>(
            qkvb, qkvb + 4194304, vtb, rid, qEcb, attnb);

        // O projection, split-K x2 -> partials proj, ffin
        gemm_bt<0><<<dim3(8, 32, 2), 256, 0, stream>>>(
            attnb, wo_t, bo + l * 1024, nullptr, nullptr,
            proj, ffin, nullptr, nullptr, nullptr, 4096, 1024, 1024, 512);

        // ff_in = LN(x + proj + ffin)   (writes ffin in-place: per-thread safe)
        ln_kernel<2><<<4096, 256, 0, stream>>>(
            xcur, proj, ffin, nullptr, nullptr,
            g1 + l * 1024, be1 + l * 1024, ffin, ffinb);

        // FFN1: relu(ffin @ W1 + b1) -> bf16 hb
        gemm_bt<1><<<dim3(32, 32, 1), 256, 0, stream>>>(
            ffinb, w1_t, b1 + l * 4096, nullptr, nullptr,
            nullptr, nullptr, nullptr, nullptr, hb, 4096, 4096, 1024, 1024);

        // FFN2: hb @ W2 + b2, split-K x4 -> partials proj, xf, attnb-region, wqkv-region
        gemm_bt<0><<<dim3(8, 32, 4), 256, 0, stream>>>(
            hb, w2_t, b2 + l * 1024, nullptr, nullptr,
            proj, xf, pP2, pP3, nullptr, 4096, 1024, 4096, 1024);

        // x_next = LN(ffin + sum of 4 partials)
        float* lnout = (l == 5) ? (float*)d_out : xf;
        unsigned short* lnoutb = (l == 5) ? nullptr : xb;
        ln_kernel<4><<<4096, 256, 0, stream>>>(
            ffin, proj, xf, pP2, pP3,
            g2 + l * 1024, be2 + l * 1024, lnout, lnoutb);
        xcur = xf;
    }
}

// Round 6
// 2271.706 us; speedup vs baseline: 1.3337x; 1.0503x over previous
//
#include <hip/hip_runtime.h>

typedef __attribute__((ext_vector_type(8))) short short8;
typedef __attribute__((ext_vector_type(4))) float f32x4;
typedef __attribute__((ext_vector_type(4))) unsigned short ushort4v;

#define AS1(p) ((const __attribute__((address_space(1))) void*)(p))
#define AS3(p) ((__attribute__((address_space(3))) void*)(p))

__device__ __forceinline__ float bf2f(unsigned short v) {
    union { unsigned u; float f; } c; c.u = ((unsigned)v) << 16; return c.f;
}
__device__ __forceinline__ unsigned short f2bf(float f) {
    union { float f; unsigned u; } c; c.f = f;
    unsigned u = c.u;
    return (unsigned short)((u + 0x7FFFu + ((u >> 16) & 1u)) >> 16);
}

// ---------------------------------------------------------------------------
// fp32 [R][C] -> bf16 [C][R] transpose+convert (weights), 64x64 tiles,
// f32x4 loads + ushort4 stores (was 32x32 scalar).
// ---------------------------------------------------------------------------
__global__ __launch_bounds__(256) void transpose_cvt(
    const float* __restrict__ in, unsigned short* __restrict__ out, int R, int C)
{
    __shared__ float tile[64][68];
    int bx = blockIdx.x * 64;            // C dim
    int by = blockIdx.y * 64;            // R dim
    int tx = threadIdx.x & 15, ty = threadIdx.x >> 4;   // 16 x 16
    #pragma unroll
    for (int i = 0; i < 4; i++) {
        int r = ty + i * 16;
        f32x4 v = *(const f32x4*)(in + (size_t)(by + r) * C + bx + tx * 4);
        *(f32x4*)&tile[r][tx * 4] = v;
    }
    __syncthreads();
    #pragma unroll
    for (int i = 0; i < 4; i++) {
        int c = ty + i * 16;
        ushort4v o = { f2bf(tile[tx * 4 + 0][c]), f2bf(tile[tx * 4 + 1][c]),
                       f2bf(tile[tx * 4 + 2][c]), f2bf(tile[tx * 4 + 3][c]) };
        *(ushort4v*)(out + (size_t)(bx + c) * R + by + tx * 4) = o;
    }
}

// ---------------------------------------------------------------------------
__global__ __launch_bounds__(256) void cvt_f32_bf16(
    const float* __restrict__ in, unsigned short* __restrict__ out, int n)
{
    int i4 = (blockIdx.x * 256 + threadIdx.x) * 4;
    if (i4 < n) {
        f32x4 v = *(const f32x4*)(in + i4);
        ushort4v o = { f2bf(v[0]), f2bf(v[1]), f2bf(v[2]), f2bf(v[3]) };
        *(ushort4v*)(out + i4) = o;
    }
}

// ---------------------------------------------------------------------------
// bf16 per-bh transpose: in [64 bh][1024 s][64 d] -> out [64 bh][64 d][1024 s]
// ---------------------------------------------------------------------------
__global__ __launch_bounds__(256) void transpose_v(
    const unsigned short* __restrict__ in, unsigned short* __restrict__ out)
{
    __shared__ unsigned short t[64][66];
    int bh = blockIdx.y, s0 = blockIdx.x * 64;
    int tid = threadIdx.x;
    int r = tid >> 2, c = (tid & 3) * 16;
    const unsigned short* ip = in + ((size_t)bh * 1024 + s0 + r) * 64 + c;
    short8 a0 = *(const short8*)ip;
    short8 a1 = *(const short8*)(ip + 8);
    #pragma unroll
    for (int i = 0; i < 8; i++) t[r][c + i] = (unsigned short)a0[i];
    #pragma unroll
    for (int i = 0; i < 8; i++) t[r][c + 8 + i] = (unsigned short)a1[i];
    __syncthreads();
    int d = tid >> 2, sc = (tid & 3) * 16;
    short8 v0, v1;
    #pragma unroll
    for (int i = 0; i < 8; i++) v0[i] = (short)t[sc + i][d];
    #pragma unroll
    for (int i = 0; i < 8; i++) v1[i] = (short)t[sc + 8 + i][d];
    unsigned short* op = out + ((size_t)bh * 64 + d) * 1024 + s0 + sc;
    *(short8*)op = v0;
    *(short8*)(op + 8) = v1;
}

// ---------------------------------------------------------------------------
// 128x128 GEMM, 2-phase double-buffered, XCD-chunk swizzled (T1):
// hardware linear block id round-robins across 8 XCD L2s; the bijective
// remap (lin&7)*cpx + lin>>3 gives each XCD a CONTIGUOUS logical range
// (m-row-major, n-fast) so A-row panels are fetched once per XCD and the
// z (split-K) slices separate per XCD instead of thrashing one L2.
// MODE 0: fp32 out (split-K: z selects K-chunk + partial buffer; bias only
// z==0). MODE 1: bf16 relu(x+bias0). MODE 2: qkv scatter.
// ---------------------------------------------------------------------------
template <int MODE>
__global__ __launch_bounds__(256)
void gemm_bt(const unsigned short* __restrict__ A,
             const unsigned short* __restrict__ Bt,
             const float* __restrict__ bias0,
             const float* __restrict__ bias1,
             const float* __restrict__ bias2,
             float* __restrict__ outF0,
             float* __restrict__ outF1,
             float* __restrict__ outF2,
             float* __restrict__ outF3,
             unsigned short* __restrict__ outB,
             int M, int N, int K, int Kc)
{
    __shared__ __align__(16) unsigned short As[2][128 * 32];   // [m][k]
    __shared__ __align__(16) unsigned short Bs[2][128 * 32];   // [n][k]

    int tid = threadIdx.x;
    int wave = tid >> 6, lane = tid & 63;
    int ml = lane & 15, quad = lane >> 4;

    // XCD swizzle (total % 8 == 0 for all launches of this kernel)
    int nx = gridDim.x, ny = gridDim.y;
    int nwg = nx * ny;
    int lin = blockIdx.x + nx * (blockIdx.y + ny * blockIdx.z);
    int total = nwg * gridDim.z;
    int cpx = total >> 3;
    int logical = (lin & 7) * cpx + (lin >> 3);
    int z = logical / nwg;
    int rem = logical - z * nwg;
    int m0 = (rem / nx) * 128, n0 = (rem % nx) * 128;

    int wm = (wave >> 1) * 64, wn = (wave & 1) * 64;

    f32x4 acc[4][4];
    #pragma unroll
    for (int i = 0; i < 4; i++)
        #pragma unroll
        for (int j = 0; j < 4; j++)
            #pragma unroll
            for (int r = 0; r < 4; r++) acc[i][j][r] = 0.0f;

    int srow = lane >> 2, skp = (lane & 3) * 8;
    int kbeg = z * Kc;
    int nt = Kc >> 5;

    auto stage = [&](int buf, int k0) {
        #pragma unroll
        for (int c2 = 0; c2 < 2; c2++) {
            int c = wave + c2 * 4;
            const unsigned short* ga = A + (size_t)(m0 + c * 16 + srow) * K + (k0 + skp);
            __builtin_amdgcn_global_load_lds(AS1(ga), AS3(&As[buf][c * 512]), 16, 0, 0);
            const unsigned short* gb = Bt + (size_t)(n0 + c * 16 + srow) * K + (k0 + skp);
            __builtin_amdgcn_global_load_lds(AS1(gb), AS3(&Bs[buf][c * 512]), 16, 0, 0);
        }
    };

    stage(0, kbeg);
    __syncthreads();

    for (int t = 0; t < nt; t++) {
        int cur = t & 1;
        if (t + 1 < nt) stage(cur ^ 1, kbeg + (t + 1) * 32);

        short8 af[4], bfr[4];
        #pragma unroll
        for (int i = 0; i < 4; i++)
            af[i] = *(const short8*)(&As[cur][(wm + i * 16 + ml) * 32 + quad * 8]);
        #pragma unroll
        for (int j = 0; j < 4; j++)
            bfr[j] = *(const short8*)(&Bs[cur][(wn + j * 16 + ml) * 32 + quad * 8]);
        #pragma unroll
        for (int i = 0; i < 4; i++)
            #pragma unroll
            for (int j = 0; j < 4; j++)
                acc[i][j] = __builtin_amdgcn_mfma_f32_16x16x32_bf16(af[i], bfr[j], acc[i][j], 0, 0, 0);

        if (t + 1 < nt) __syncthreads();
    }

    float* outF = (z == 0) ? outF0 : (z == 1) ? outF1 : (z == 2) ? outF2 : outF3;

    size_t Ns = (size_t)N;
    #pragma unroll
    for (int j = 0; j < 4; j++) {
        int ng = n0 + wn + j * 16 + ml;
        float bv;
        if (MODE == 2) {
            int which = ng >> 10;
            const float* bp = (which == 0) ? bias0 : ((which == 1) ? bias1 : bias2);
            bv = bp[ng & 1023];
        } else {
            bv = (z == 0) ? bias0[ng] : 0.0f;
        }
        #pragma unroll
        for (int i = 0; i < 4; i++) {
            #pragma unroll
            for (int r = 0; r < 4; r++) {
                int mg = m0 + wm + i * 16 + quad * 4 + r;
                float v = acc[i][j][r] + bv;
                if (MODE == 0) {
                    outF[(size_t)mg * Ns + ng] = v;
                } else if (MODE == 1) {
                    outB[(size_t)mg * Ns + ng] = f2bf(fmaxf(v, 0.0f));
                } else {
                    int which = ng >> 10, wi = ng & 1023;
                    int h = wi >> 6, d = wi & 63;
                    int b = mg >> 10, s = mg & 1023;
                    outB[(size_t)which * 4194304 +
                         ((size_t)(b * 16 + h) * 1024 + s) * 64 + d] = f2bf(v);
                }
            }
        }
    }
}

// ---------------------------------------------------------------------------
// qEc[b,h,s,n] = ( q[b,h,s,:] . Erel[n,:] + Brel[h,n] ) * scale
// ---------------------------------------------------------------------------
__global__ __launch_bounds__(256) void qe_kernel(
    const unsigned short* __restrict__ q,     // [B,H,S,64] bf16
    const float* __restrict__ Erel,           // [33][64]
    const float* __restrict__ Brel,           // [16][33]
    float* __restrict__ out)                  // [B,H,S,33]
{
    int idx = blockIdx.x * 256 + threadIdx.x;
    if (idx >= 2162688) return;
    int n = idx % 33;
    int row = idx / 33;
    const short8* qv = (const short8*)(q + (size_t)row * 64);
    float s = 0.0f;
    #pragma unroll
    for (int c = 0; c < 8; c++) {
        short8 qq = qv[c];
        const float* e = Erel + n * 64 + c * 8;
        #pragma unroll
        for (int j = 0; j < 8; j++) s += bf2f((unsigned short)qq[j]) * e[j];
    }
    int h = (row >> 10) & 15;
    out[idx] = (s + Brel[h * 33 + n]) * 0.125f;
}

// ---------------------------------------------------------------------------
// Flash attention (R2 structure: LDS-staged K/V, register prefetch, 2
// barriers/tile) + softmax de-serialization (R5):
//  - T13 defer-max with LANE-LOCAL check (common path: zero shuffles).
//  - lane-local l accumulation; single cross-lane reduce in epilogue.
//  - rid gather hoisted above QK^T; T5 setprio around MFMA clusters.
// ---------------------------------------------------------------------------
__global__ __launch_bounds__(256, 3)
void attn_kernel(const unsigned short* __restrict__ Q,   // [B,H,S,64]
                 const unsigned short* __restrict__ Kin, // [B,H,S,64]
                 const unsigned short* __restrict__ Vt,  // [B,H,64,S]
                 const int* __restrict__ rid,            // [S,S]
                 const float* __restrict__ qEc,          // [B,H,S,33] prescaled incl Brel
                 unsigned short* __restrict__ outp)      // [B,S,H*64]
{
    const float scale = 0.125f;
    int bid = blockIdx.x;
    int bh = bid & 63, qt = bid >> 6;
    int b = bh >> 4, h = bh & 15;
    int q0 = qt * 64;
    size_t bhs = (size_t)bh;

    __shared__ __align__(16) unsigned short Ks[64 * 72];
    __shared__ __align__(16) unsigned short VT[64 * 72];
    __shared__ __align__(16) unsigned short Ps[4][16 * 72];
    __shared__ float combS[4][528];

    int tid = threadIdx.x;
    int wave = tid >> 6, lane = tid & 63;
    int ml = lane & 15, quad = lane >> 4;

    const unsigned short* Qp = Q + (bhs * 1024 + q0) * 64;
    const unsigned short* Kp = Kin + bhs * 65536;
    const unsigned short* Vp = Vt + bhs * 65536;

    // Q fragments (A layout), per-wave 16-row strip, loaded once
    short8 aq0 = *(const short8*)(Qp + (size_t)(wave * 16 + ml) * 64 + quad * 8);
    short8 aq1 = *(const short8*)(Qp + (size_t)(wave * 16 + ml) * 64 + 32 + quad * 8);

    // comb strip: rows [q0+wave*16, +16), 33 floats each, contiguous
    {
        const float* qEw = qEc + (bhs * 1024 + q0 + wave * 16) * 33;
        for (int i = lane; i < 528; i += 64) combS[wave][i] = qEw[i];
    }

    // staging coords: 64 rows x 64 cols, thread -> (row, 16-col chunk)
    int srow = tid >> 2, scol = (tid & 3) * 16;
    const unsigned short* Kg = Kp + (size_t)srow * 64 + scol;        // +kt*64*64
    const unsigned short* Vg = Vp + (size_t)srow * 1024 + scol;      // +kt*64
    // rid gather rows for this lane: q = q0 + wave*16 + quad*4 + r
    const int* ridBase = rid + (size_t)(q0 + wave * 16 + quad * 4) * 1024;

    float m_st[4], l_st[4];
    f32x4 o_acc[4];
    #pragma unroll
    for (int r = 0; r < 4; r++) { m_st[r] = -1e30f; l_st[r] = 0.0f; }
    #pragma unroll
    for (int j = 0; j < 4; j++)
        #pragma unroll
        for (int r = 0; r < 4; r++) o_acc[j][r] = 0.0f;

    // prefetch tile 0
    short8 pk0 = *(const short8*)(Kg);
    short8 pk1 = *(const short8*)(Kg + 8);
    short8 pv0 = *(const short8*)(Vg);
    short8 pv1 = *(const short8*)(Vg + 8);

    for (int kt = 0; kt < 16; kt++) {
        if (kt > 0) __syncthreads();            // prev compute done before overwrite
        *(short8*)(Ks + srow * 72 + scol)     = pk0;
        *(short8*)(Ks + srow * 72 + scol + 8) = pk1;
        *(short8*)(VT + srow * 72 + scol)     = pv0;
        *(short8*)(VT + srow * 72 + scol + 8) = pv1;
        __syncthreads();

        if (kt + 1 < 16) {                      // prefetch next tile (in flight over compute)
            pk0 = *(const short8*)(Kg + (kt + 1) * 4096);
            pk1 = *(const short8*)(Kg + (kt + 1) * 4096 + 8);
            pv0 = *(const short8*)(Vg + (kt + 1) * 64);
            pv1 = *(const short8*)(Vg + (kt + 1) * 64 + 8);
        }

        // rid gather: issue before QK^T so L2 latency hides under MFMA
        int rv[4][4];
        #pragma unroll
        for (int r = 0; r < 4; r++) {
            const int* rp = ridBase + (size_t)r * 1024 + kt * 64 + ml;
            #pragma unroll
            for (int j = 0; j < 4; j++) rv[r][j] = rp[j * 16];
        }

        // QK^T
        f32x4 s_acc[4];
        #pragma unroll
        for (int j = 0; j < 4; j++)
            #pragma unroll
            for (int r = 0; r < 4; r++) s_acc[j][r] = 0.0f;
        __builtin_amdgcn_s_setprio(1);
        #pragma unroll
        for (int j = 0; j < 4; j++) {
            short8 bk0 = *(const short8*)(Ks + (j * 16 + ml) * 72 + quad * 8);
            short8 bk1 = *(const short8*)(Ks + (j * 16 + ml) * 72 + 32 + quad * 8);
            s_acc[j] = __builtin_amdgcn_mfma_f32_16x16x32_bf16(aq0, bk0, s_acc[j], 0, 0, 0);
            s_acc[j] = __builtin_amdgcn_mfma_f32_16x16x32_bf16(aq1, bk1, s_acc[j], 0, 0, 0);
        }
        __builtin_amdgcn_s_setprio(0);

        // rel score add + LANE-LOCAL row max
        float mxl[4];
        #pragma unroll
        for (int r = 0; r < 4; r++) {
            int rl = quad * 4 + r;
            #pragma unroll
            for (int j = 0; j < 4; j++)
                s_acc[j][r] = s_acc[j][r] * scale + combS[wave][rl * 33 + rv[r][j]];
            mxl[r] = fmaxf(fmaxf(s_acc[0][r], s_acc[1][r]), fmaxf(s_acc[2][r], s_acc[3][r]));
        }

        // defer-max: all(lane_max <= m+8)  <=>  row_max <= m+8
        bool ok = (mxl[0] <= m_st[0] + 8.0f) & (mxl[1] <= m_st[1] + 8.0f)
                & (mxl[2] <= m_st[2] + 8.0f) & (mxl[3] <= m_st[3] + 8.0f);
        if (__all(ok)) {
            // common path: no shuffles, no rescale
            #pragma unroll
            for (int r = 0; r < 4; r++) {
                int rl = quad * 4 + r;
                float ps = 0.0f;
                #pragma unroll
                for (int j = 0; j < 4; j++) {
                    float pv = __expf(s_acc[j][r] - m_st[r]);
                    ps += pv;
                    Ps[wave][rl * 72 + j * 16 + ml] = f2bf(pv);
                }
                l_st[r] += ps;          // lane-local partial
            }
        } else {
            #pragma unroll
            for (int r = 0; r < 4; r++) {
                int rl = quad * 4 + r;
                float m0 = mxl[r];
                m0 = fmaxf(m0, __shfl_xor(m0, 1, 64));
                m0 = fmaxf(m0, __shfl_xor(m0, 2, 64));
                m0 = fmaxf(m0, __shfl_xor(m0, 4, 64));
                m0 = fmaxf(m0, __shfl_xor(m0, 8, 64));
                float mnew = fmaxf(m_st[r], m0);
                float alpha = __expf(m_st[r] - mnew);   // row-uniform
                float ps = 0.0f;
                #pragma unroll
                for (int j = 0; j < 4; j++) {
                    float pv = __expf(s_acc[j][r] - mnew);
                    ps += pv;
                    Ps[wave][rl * 72 + j * 16 + ml] = f2bf(pv);
                }
                l_st[r] = l_st[r] * alpha + ps;         // lane-local partial
                m_st[r] = mnew;
                #pragma unroll
                for (int j = 0; j < 4; j++) o_acc[j][r] *= alpha;
            }
        }

        // P.V: A from per-wave Ps, B from VT (both LDS)
        short8 ap0 = *(const short8*)(&Ps[wave][ml * 72 + quad * 8]);
        short8 ap1 = *(const short8*)(&Ps[wave][ml * 72 + 32 + quad * 8]);
        __builtin_amdgcn_s_setprio(1);
        #pragma unroll
        for (int j = 0; j < 4; j++) {
            short8 bv0 = *(const short8*)(VT + (j * 16 + ml) * 72 + quad * 8);
            short8 bv1 = *(const short8*)(VT + (j * 16 + ml) * 72 + 32 + quad * 8);
            o_acc[j] = __builtin_amdgcn_mfma_f32_16x16x32_bf16(ap0, bv0, o_acc[j], 0, 0, 0);
            o_acc[j] = __builtin_amdgcn_mfma_f32_16x16x32_bf16(ap1, bv1, o_acc[j], 0, 0, 0);
        }
        __builtin_amdgcn_s_setprio(0);
    }

    // epilogue: reduce lane-local l partials across the 16 lanes of each row
    #pragma unroll
    for (int r = 0; r < 4; r++) {
        float lr = l_st[r];
        lr += __shfl_xor(lr, 1, 64);
        lr += __shfl_xor(lr, 2, 64);
        lr += __shfl_xor(lr, 4, 64);
        lr += __shfl_xor(lr, 8, 64);
        int qrow = wave * 16 + quad * 4 + r;
        float invl = 1.0f / lr;
        size_t base = ((size_t)(b * 1024 + q0 + qrow)) * 1024 + h * 64;
        #pragma unroll
        for (int j = 0; j < 4; j++)
            outp[base + j * 16 + ml] = f2bf(o_acc[j][r] * invl);
    }
}

// ---------------------------------------------------------------------------
// LayerNorm( a + p0 [+ p1 [+ p2 [+ p3]]] ) * g + be  -> fp32 out (+ bf16 out).
// D = 1024. NP = number of partial buffers summed onto a.
// In-place safe: each thread reads its own 4 elements before writing them.
// ---------------------------------------------------------------------------
template <int NP>
__global__ __launch_bounds__(256) void ln_kernel(
    const float* __restrict__ a,
    const float* __restrict__ p0, const float* __restrict__ p1,
    const float* __restrict__ p2, const float* __restrict__ p3,
    const float* __restrict__ g, const float* __restrict__ be,
    float* __restrict__ outF, unsigned short* __restrict__ outB)
{
    int row = blockIdx.x, tid = threadIdx.x;
    int wave = tid >> 6, lane = tid & 63;
    size_t off = (size_t)row * 1024 + tid * 4;
    f32x4 x = *(const f32x4*)(a + off);
    {
        f32x4 t = *(const f32x4*)(p0 + off);
        #pragma unroll
        for (int i = 0; i < 4; i++) x[i] += t[i];
    }
    if (NP > 1) {
        f32x4 t = *(const f32x4*)(p1 + off);
        #pragma unroll
        for (int i = 0; i < 4; i++) x[i] += t[i];
    }
    if (NP > 2) {
        f32x4 t = *(const f32x4*)(p2 + off);
        #pragma unroll
        for (int i = 0; i < 4; i++) x[i] += t[i];
    }
    if (NP > 3) {
        f32x4 t = *(const f32x4*)(p3 + off);
        #pragma unroll
        for (int i = 0; i < 4; i++) x[i] += t[i];
    }
    float s1 = x[0] + x[1] + x[2] + x[3];
    float s2 = x[0]*x[0] + x[1]*x[1] + x[2]*x[2] + x[3]*x[3];
    #pragma unroll
    for (int offx = 1; offx < 64; offx <<= 1) {
        s1 += __shfl_xor(s1, offx, 64);
        s2 += __shfl_xor(s2, offx, 64);
    }
    __shared__ float r1[4], r2[4];
    if (lane == 0) { r1[wave] = s1; r2[wave] = s2; }
    __syncthreads();
    s1 = r1[0] + r1[1] + r1[2] + r1[3];
    s2 = r2[0] + r2[1] + r2[2] + r2[3];
    float mean = s1 * (1.0f / 1024.0f);
    float var  = s2 * (1.0f / 1024.0f) - mean * mean;
    float inv  = rsqrtf(var + 1e-6f);
    f32x4 gg = *(const f32x4*)(g + tid * 4);
    f32x4 bb = *(const f32x4*)(be + tid * 4);
    f32x4 o;
    #pragma unroll
    for (int i = 0; i < 4; i++) o[i] = (x[i] - mean) * inv * gg[i] + bb[i];
    *(f32x4*)(outF + off) = o;
    if (outB != nullptr) {
        ushort4v ov = { f2bf(o[0]), f2bf(o[1]), f2bf(o[2]), f2bf(o[3]) };
        *(ushort4v*)(outB + off) = ov;
    }
}

// ---------------------------------------------------------------------------
extern "C" void kernel_launch(void* const* d_in, const int* in_sizes, int n_in,
                              void* d_out, int out_size, void* d_ws, size_t ws_size,
                              hipStream_t stream)
{
    const float* x_in = (const float*)d_in[0];
    const int*   rid  = (const int*)d_in[1];
    const float* Wq = (const float*)d_in[2];  const float* bq = (const float*)d_in[3];
    const float* Wk = (const float*)d_in[4];  const float* bk = (const float*)d_in[5];
    const float* Wv = (const float*)d_in[6];  const float* bv = (const float*)d_in[7];
    const float* Wo = (const float*)d_in[8];  const float* bo = (const float*)d_in[9];
    const float* Erel = (const float*)d_in[10];
    const float* Brel = (const float*)d_in[11];
    const float* g1 = (const float*)d_in[12]; const float* be1 = (const float*)d_in[13];
    const float* g2 = (const float*)d_in[14]; const float* be2 = (const float*)d_in[15];
    const float* W1 = (const float*)d_in[16]; const float* b1 = (const float*)d_in[17];
    const float* W2 = (const float*)d_in[18]; const float* b2 = (const float*)d_in[19];

    char* p = (char*)d_ws;
    auto alloc = [&](size_t bytes) {
        char* r = p; p += (bytes + 255) & ~(size_t)255; return (void*)r;
    };
    unsigned short* wqkv_t = (unsigned short*)alloc(3ull * 1024 * 1024 * 2); // [3072][1024]
    unsigned short* wo_t   = (unsigned short*)alloc(1024ull * 1024 * 2);
    unsigned short* w1_t   = (unsigned short*)alloc(4096ull * 1024 * 2);
    unsigned short* w2_t   = (unsigned short*)alloc(1024ull * 4096 * 2);
    float*          xf     = (float*)alloc(4096ull * 1024 * 4);
    unsigned short* xb     = (unsigned short*)alloc(4096ull * 1024 * 2);
    unsigned short* qkvb   = (unsigned short*)alloc(3ull * 4194304 * 2);     // q|k|v
    unsigned short* vtb    = (unsigned short*)alloc(4194304ull * 2);         // V^T [B,H,64,S]
    unsigned short* attnb  = (unsigned short*)alloc(4096ull * 1024 * 2);
    float*          qEcb   = (float*)alloc(2162688ull * 4);                  // [B,H,S,33]
    float*          proj   = (float*)alloc(4096ull * 1024 * 4);
    float*          ffin   = (float*)alloc(4096ull * 1024 * 4);
    unsigned short* ffinb  = (unsigned short*)alloc(4096ull * 1024 * 2);
    unsigned short* hb     = qkvb;   // 32MB reuse (qkvb dead by FFN1; spans into vtb)

    // Split-K partial buffers, all reusing dead regions at their point of use:
    //  O-proj (z=2):  P0 = proj, P1 = ffin            (ffin dead until LN1 writes it)
    //  FFN2   (z=4):  P0 = proj, P1 = xf              (residual already consumed by LN1)
    //                 P2 = attnb∪qEcb (17.0 MB contig, both consumed)
    //                 P3 = wqkv_t∪wo_t∪w1_t (exactly 16.78 MB contig, weights consumed;
    //                      rewritten only at next layer's transpose, after LN2)
    float* pP2 = (float*)attnb;
    float* pP3 = (float*)wqkv_t;

    cvt_f32_bf16<<<4096, 256, 0, stream>>>(x_in, xb, 4194304);

    const float* xcur = x_in;
    for (int l = 0; l < 6; l++) {
        transpose_cvt<<<dim3(16, 16), 256, 0, stream>>>(Wq + (size_t)l * 1048576, wqkv_t,           1024, 1024);
        transpose_cvt<<<dim3(16, 16), 256, 0, stream>>>(Wk + (size_t)l * 1048576, wqkv_t + 1048576, 1024, 1024);
        transpose_cvt<<<dim3(16, 16), 256, 0, stream>>>(Wv + (size_t)l * 1048576, wqkv_t + 2097152, 1024, 1024);
        transpose_cvt<<<dim3(16, 16), 256, 0, stream>>>(Wo + (size_t)l * 1048576, wo_t,             1024, 1024);
        transpose_cvt<<<dim3(64, 16), 256, 0, stream>>>(W1 + (size_t)l * 4194304, w1_t, 1024, 4096);
        transpose_cvt<<<dim3(16, 64), 256, 0, stream>>>(W2 + (size_t)l * 4194304, w2_t, 4096, 1024);

        // QKV fused: [4096,1024] @ [1024,3072] -> q,k,v [B,H,S,64]
        gemm_bt<2><<<dim3(24, 32, 1), 256, 0, stream>>>(
            xb, wqkv_t, bq + l * 1024, bk + l * 1024, bv + l * 1024,
            nullptr, nullptr, nullptr, nullptr, qkvb, 4096, 3072, 1024, 1024);

        transpose_v<<<dim3(16, 64), 256, 0, stream>>>(qkvb + 8388608, vtb);

        qe_kernel<<<8448, 256, 0, stream>>>(qkvb, Erel + l * 2112, Brel + l * 528, qEcb);

        attn_kernel<<<1024, 256, 0, stream>>>(
            qkvb, qkvb + 4194304, vtb, rid, qEcb, attnb);

        // O projection, split-K x2 -> partials proj, ffin
        gemm_bt<0><<<dim3(8, 32, 2), 256, 0, stream>>>(
            attnb, wo_t, bo + l * 1024, nullptr, nullptr,
            proj, ffin, nullptr, nullptr, nullptr, 4096, 1024, 1024, 512);

        // ff_in = LN(x + proj + ffin)   (writes ffin in-place: per-thread safe)
        ln_kernel<2><<<4096, 256, 0, stream>>>(
            xcur, proj, ffin, nullptr, nullptr,
            g1 + l * 1024, be1 + l * 1024, ffin, ffinb);

        // FFN1: relu(ffin @ W1 + b1) -> bf16 hb
        gemm_bt<1><<<dim3(32, 32, 1), 256, 0, stream>>>(
            ffinb, w1_t, b1 + l * 4096, nullptr, nullptr,
            nullptr, nullptr, nullptr, nullptr, hb, 4096, 4096, 1024, 1024);

        // FFN2: hb @ W2 + b2, split-K x4 -> partials proj, xf, attnb-region, wqkv-region
        gemm_bt<0><<<dim3(8, 32, 4), 256, 0, stream>>>(
            hb, w2_t, b2 + l * 1024, nullptr, nullptr,
            proj, xf, pP2, pP3, nullptr, 4096, 1024, 4096, 1024);

        // x_next = LN(ffin + sum of 4 partials)
        float* lnout = (l == 5) ? (float*)d_out : xf;
        unsigned short* lnoutb = (l == 5) ? nullptr : xb;
        ln_kernel<4><<<4096, 256, 0, stream>>>(
            ffin, proj, xf, pP2, pP3,
            g2 + l * 1024, be2 + l * 1024, lnout, lnoutb);
        xcur = xf;
    }
}

// Round 7
// 1937.454 us; speedup vs baseline: 1.5638x; 1.1725x over previous
//
#include <hip/hip_runtime.h>

typedef __attribute__((ext_vector_type(8))) short short8;
typedef __attribute__((ext_vector_type(4))) float f32x4;
typedef __attribute__((ext_vector_type(4))) unsigned short ushort4v;

#define AS1(p) ((const __attribute__((address_space(1))) void*)(p))
#define AS3(p) ((__attribute__((address_space(3))) void*)(p))

__device__ __forceinline__ float bf2f(unsigned short v) {
    union { unsigned u; float f; } c; c.u = ((unsigned)v) << 16; return c.f;
}
__device__ __forceinline__ unsigned short f2bf(float f) {
    union { float f; unsigned u; } c; c.f = f;
    unsigned u = c.u;
    return (unsigned short)((u + 0x7FFFu + ((u >> 16) & 1u)) >> 16);
}

// ---------------------------------------------------------------------------
// fp32 [R][C] -> bf16 [C][R] transpose+convert (weights), 64x64 tiles,
// f32x4 loads + ushort4 stores.
// ---------------------------------------------------------------------------
__global__ __launch_bounds__(256) void transpose_cvt(
    const float* __restrict__ in, unsigned short* __restrict__ out, int R, int C)
{
    __shared__ float tile[64][68];
    int bx = blockIdx.x * 64;            // C dim
    int by = blockIdx.y * 64;            // R dim
    int tx = threadIdx.x & 15, ty = threadIdx.x >> 4;   // 16 x 16
    #pragma unroll
    for (int i = 0; i < 4; i++) {
        int r = ty + i * 16;
        f32x4 v = *(const f32x4*)(in + (size_t)(by + r) * C + bx + tx * 4);
        *(f32x4*)&tile[r][tx * 4] = v;
    }
    __syncthreads();
    #pragma unroll
    for (int i = 0; i < 4; i++) {
        int c = ty + i * 16;
        ushort4v o = { f2bf(tile[tx * 4 + 0][c]), f2bf(tile[tx * 4 + 1][c]),
                       f2bf(tile[tx * 4 + 2][c]), f2bf(tile[tx * 4 + 3][c]) };
        *(ushort4v*)(out + (size_t)(bx + c) * R + by + tx * 4) = o;
    }
}

// ---------------------------------------------------------------------------
__global__ __launch_bounds__(256) void cvt_f32_bf16(
    const float* __restrict__ in, unsigned short* __restrict__ out, int n)
{
    int i4 = (blockIdx.x * 256 + threadIdx.x) * 4;
    if (i4 < n) {
        f32x4 v = *(const f32x4*)(in + i4);
        ushort4v o = { f2bf(v[0]), f2bf(v[1]), f2bf(v[2]), f2bf(v[3]) };
        *(ushort4v*)(out + i4) = o;
    }
}

// ---------------------------------------------------------------------------
// bf16 per-bh transpose: in [64 bh][1024 s][64 d] -> out [64 bh][64 d][1024 s]
// ---------------------------------------------------------------------------
__global__ __launch_bounds__(256) void transpose_v(
    const unsigned short* __restrict__ in, unsigned short* __restrict__ out)
{
    __shared__ unsigned short t[64][66];
    int bh = blockIdx.y, s0 = blockIdx.x * 64;
    int tid = threadIdx.x;
    int r = tid >> 2, c = (tid & 3) * 16;
    const unsigned short* ip = in + ((size_t)bh * 1024 + s0 + r) * 64 + c;
    short8 a0 = *(const short8*)ip;
    short8 a1 = *(const short8*)(ip + 8);
    #pragma unroll
    for (int i = 0; i < 8; i++) t[r][c + i] = (unsigned short)a0[i];
    #pragma unroll
    for (int i = 0; i < 8; i++) t[r][c + 8 + i] = (unsigned short)a1[i];
    __syncthreads();
    int d = tid >> 2, sc = (tid & 3) * 16;
    short8 v0, v1;
    #pragma unroll
    for (int i = 0; i < 8; i++) v0[i] = (short)t[sc + i][d];
    #pragma unroll
    for (int i = 0; i < 8; i++) v1[i] = (short)t[sc + 8 + i][d];
    unsigned short* op = out + ((size_t)bh * 64 + d) * 1024 + s0 + sc;
    *(short8*)op = v0;
    *(short8*)(op + 8) = v1;
}

// ---------------------------------------------------------------------------
// 128x128 GEMM, 2-phase double-buffered, XCD-chunk swizzled (T1).
// MODE 0: fp32 out (split-K: z selects K-chunk + partial buffer; bias only
// z==0). MODE 1: bf16 relu(x+bias0). MODE 2: qkv scatter.
// ---------------------------------------------------------------------------
template <int MODE>
__global__ __launch_bounds__(256)
void gemm_bt(const unsigned short* __restrict__ A,
             const unsigned short* __restrict__ Bt,
             const float* __restrict__ bias0,
             const float* __restrict__ bias1,
             const float* __restrict__ bias2,
             float* __restrict__ outF0,
             float* __restrict__ outF1,
             float* __restrict__ outF2,
             float* __restrict__ outF3,
             unsigned short* __restrict__ outB,
             int M, int N, int K, int Kc)
{
    __shared__ __align__(16) unsigned short As[2][128 * 32];   // [m][k]
    __shared__ __align__(16) unsigned short Bs[2][128 * 32];   // [n][k]

    int tid = threadIdx.x;
    int wave = tid >> 6, lane = tid & 63;
    int ml = lane & 15, quad = lane >> 4;

    // XCD swizzle (total % 8 == 0 for all launches of this kernel)
    int nx = gridDim.x, ny = gridDim.y;
    int nwg = nx * ny;
    int lin = blockIdx.x + nx * (blockIdx.y + ny * blockIdx.z);
    int total = nwg * gridDim.z;
    int cpx = total >> 3;
    int logical = (lin & 7) * cpx + (lin >> 3);
    int z = logical / nwg;
    int rem = logical - z * nwg;
    int m0 = (rem / nx) * 128, n0 = (rem % nx) * 128;

    int wm = (wave >> 1) * 64, wn = (wave & 1) * 64;

    f32x4 acc[4][4];
    #pragma unroll
    for (int i = 0; i < 4; i++)
        #pragma unroll
        for (int j = 0; j < 4; j++)
            #pragma unroll
            for (int r = 0; r < 4; r++) acc[i][j][r] = 0.0f;

    int srow = lane >> 2, skp = (lane & 3) * 8;
    int kbeg = z * Kc;
    int nt = Kc >> 5;

    auto stage = [&](int buf, int k0) {
        #pragma unroll
        for (int c2 = 0; c2 < 2; c2++) {
            int c = wave + c2 * 4;
            const unsigned short* ga = A + (size_t)(m0 + c * 16 + srow) * K + (k0 + skp);
            __builtin_amdgcn_global_load_lds(AS1(ga), AS3(&As[buf][c * 512]), 16, 0, 0);
            const unsigned short* gb = Bt + (size_t)(n0 + c * 16 + srow) * K + (k0 + skp);
            __builtin_amdgcn_global_load_lds(AS1(gb), AS3(&Bs[buf][c * 512]), 16, 0, 0);
        }
    };

    stage(0, kbeg);
    __syncthreads();

    for (int t = 0; t < nt; t++) {
        int cur = t & 1;
        if (t + 1 < nt) stage(cur ^ 1, kbeg + (t + 1) * 32);

        short8 af[4], bfr[4];
        #pragma unroll
        for (int i = 0; i < 4; i++)
            af[i] = *(const short8*)(&As[cur][(wm + i * 16 + ml) * 32 + quad * 8]);
        #pragma unroll
        for (int j = 0; j < 4; j++)
            bfr[j] = *(const short8*)(&Bs[cur][(wn + j * 16 + ml) * 32 + quad * 8]);
        #pragma unroll
        for (int i = 0; i < 4; i++)
            #pragma unroll
            for (int j = 0; j < 4; j++)
                acc[i][j] = __builtin_amdgcn_mfma_f32_16x16x32_bf16(af[i], bfr[j], acc[i][j], 0, 0, 0);

        if (t + 1 < nt) __syncthreads();
    }

    float* outF = (z == 0) ? outF0 : (z == 1) ? outF1 : (z == 2) ? outF2 : outF3;

    size_t Ns = (size_t)N;
    #pragma unroll
    for (int j = 0; j < 4; j++) {
        int ng = n0 + wn + j * 16 + ml;
        float bv;
        if (MODE == 2) {
            int which = ng >> 10;
            const float* bp = (which == 0) ? bias0 : ((which == 1) ? bias1 : bias2);
            bv = bp[ng & 1023];
        } else {
            bv = (z == 0) ? bias0[ng] : 0.0f;
        }
        #pragma unroll
        for (int i = 0; i < 4; i++) {
            #pragma unroll
            for (int r = 0; r < 4; r++) {
                int mg = m0 + wm + i * 16 + quad * 4 + r;
                float v = acc[i][j][r] + bv;
                if (MODE == 0) {
                    outF[(size_t)mg * Ns + ng] = v;
                } else if (MODE == 1) {
                    outB[(size_t)mg * Ns + ng] = f2bf(fmaxf(v, 0.0f));
                } else {
                    int which = ng >> 10, wi = ng & 1023;
                    int h = wi >> 6, d = wi & 63;
                    int b = mg >> 10, s = mg & 1023;
                    outB[(size_t)which * 4194304 +
                         ((size_t)(b * 16 + h) * 1024 + s) * 64 + d] = f2bf(v);
                }
            }
        }
    }
}

// ---------------------------------------------------------------------------
// qEc[row][n] = ( q[row,:] . Erel[n,:] + Brel[h,n] ) * scale   as a skinny
// MFMA GEMM: [65536 x 64] @ [64 x 33]. Block = 128 consecutive rows (all in
// one (b,h) => h uniform); Erel converted fp32->bf16 into LDS [48][72]
// (rows 33..47 zero, stride 72 = 2-way max conflict); each wave computes
// 32 rows x 48 cols with 12 mfma_16x16x32 (fragment pattern mirrors attn).
// Replaces the per-lane Erel gather (33 cache lines per load) that made the
// old version VMEM-serialization-bound (72 us for 400 MFLOP).
// ---------------------------------------------------------------------------
__global__ __launch_bounds__(256) void qe_kernel(
    const unsigned short* __restrict__ q,     // [65536][64] bf16
    const float* __restrict__ Erel,           // [33][64]
    const float* __restrict__ Brel,           // [16][33]
    float* __restrict__ out)                  // [65536][33]
{
    __shared__ __align__(16) unsigned short El[48 * 72];
    __shared__ float brS[33];

    int tid = threadIdx.x;
    int blk = blockIdx.x;
    int h = (blk >> 3) & 15;

    // zero pad rows 33..47 (read by j=2 col-tile for n>=33)
    for (int i = tid; i < 15 * 72; i += 256) El[33 * 72 + i] = 0;
    // stage Erel -> bf16 LDS [n][k] stride 72
    for (int i = tid; i < 2112; i += 256) {
        int n = i >> 6, k = i & 63;
        El[n * 72 + k] = f2bf(Erel[i]);
    }
    if (tid < 33) brS[tid] = Brel[h * 33 + tid];
    __syncthreads();

    int wave = tid >> 6, lane = tid & 63;
    int ml = lane & 15, quad = lane >> 4;

    // A fragments: 2 row-tiles of 16 q-rows each (wave covers 32 rows)
    const unsigned short* qp = q + ((size_t)blk * 128 + wave * 32) * 64;
    short8 a0[2], a1[2];
    #pragma unroll
    for (int i = 0; i < 2; i++) {
        a0[i] = *(const short8*)(qp + (size_t)(i * 16 + ml) * 64 + quad * 8);
        a1[i] = *(const short8*)(qp + (size_t)(i * 16 + ml) * 64 + 32 + quad * 8);
    }
    // B fragments: 3 col-tiles of 16 n-rows from LDS
    short8 b0[3], b1[3];
    #pragma unroll
    for (int j = 0; j < 3; j++) {
        b0[j] = *(const short8*)(El + (j * 16 + ml) * 72 + quad * 8);
        b1[j] = *(const short8*)(El + (j * 16 + ml) * 72 + 32 + quad * 8);
    }

    f32x4 acc[2][3];
    #pragma unroll
    for (int i = 0; i < 2; i++)
        #pragma unroll
        for (int j = 0; j < 3; j++)
            #pragma unroll
            for (int r = 0; r < 4; r++) acc[i][j][r] = 0.0f;

    #pragma unroll
    for (int i = 0; i < 2; i++)
        #pragma unroll
        for (int j = 0; j < 3; j++) {
            acc[i][j] = __builtin_amdgcn_mfma_f32_16x16x32_bf16(a0[i], b0[j], acc[i][j], 0, 0, 0);
            acc[i][j] = __builtin_amdgcn_mfma_f32_16x16x32_bf16(a1[i], b1[j], acc[i][j], 0, 0, 0);
        }

    #pragma unroll
    for (int j = 0; j < 3; j++) {
        int n = j * 16 + ml;
        if (n < 33) {
            float bn = brS[n];
            #pragma unroll
            for (int i = 0; i < 2; i++) {
                #pragma unroll
                for (int r = 0; r < 4; r++) {
                    size_t row = (size_t)blk * 128 + wave * 32 + i * 16 + quad * 4 + r;
                    out[row * 33 + n] = (acc[i][j][r] + bn) * 0.125f;
                }
            }
        }
    }
}

// ---------------------------------------------------------------------------
// Flash attention (R2 structure: LDS-staged K/V, register prefetch, 2
// barriers/tile) + softmax de-serialization (R5):
//  - T13 defer-max with LANE-LOCAL check (common path: zero shuffles).
//  - lane-local l accumulation; single cross-lane reduce in epilogue.
//  - rid gather hoisted above QK^T; T5 setprio around MFMA clusters.
// ---------------------------------------------------------------------------
__global__ __launch_bounds__(256, 3)
void attn_kernel(const unsigned short* __restrict__ Q,   // [B,H,S,64]
                 const unsigned short* __restrict__ Kin, // [B,H,S,64]
                 const unsigned short* __restrict__ Vt,  // [B,H,64,S]
                 const int* __restrict__ rid,            // [S,S]
                 const float* __restrict__ qEc,          // [B,H,S,33] prescaled incl Brel
                 unsigned short* __restrict__ outp)      // [B,S,H*64]
{
    const float scale = 0.125f;
    int bid = blockIdx.x;
    int bh = bid & 63, qt = bid >> 6;
    int b = bh >> 4, h = bh & 15;
    int q0 = qt * 64;
    size_t bhs = (size_t)bh;

    __shared__ __align__(16) unsigned short Ks[64 * 72];
    __shared__ __align__(16) unsigned short VT[64 * 72];
    __shared__ __align__(16) unsigned short Ps[4][16 * 72];
    __shared__ float combS[4][528];

    int tid = threadIdx.x;
    int wave = tid >> 6, lane = tid & 63;
    int ml = lane & 15, quad = lane >> 4;

    const unsigned short* Qp = Q + (bhs * 1024 + q0) * 64;
    const unsigned short* Kp = Kin + bhs * 65536;
    const unsigned short* Vp = Vt + bhs * 65536;

    // Q fragments (A layout), per-wave 16-row strip, loaded once
    short8 aq0 = *(const short8*)(Qp + (size_t)(wave * 16 + ml) * 64 + quad * 8);
    short8 aq1 = *(const short8*)(Qp + (size_t)(wave * 16 + ml) * 64 + 32 + quad * 8);

    // comb strip: rows [q0+wave*16, +16), 33 floats each, contiguous
    {
        const float* qEw = qEc + (bhs * 1024 + q0 + wave * 16) * 33;
        for (int i = lane; i < 528; i += 64) combS[wave][i] = qEw[i];
    }

    // staging coords: 64 rows x 64 cols, thread -> (row, 16-col chunk)
    int srow = tid >> 2, scol = (tid & 3) * 16;
    const unsigned short* Kg = Kp + (size_t)srow * 64 + scol;        // +kt*64*64
    const unsigned short* Vg = Vp + (size_t)srow * 1024 + scol;      // +kt*64
    // rid gather rows for this lane: q = q0 + wave*16 + quad*4 + r
    const int* ridBase = rid + (size_t)(q0 + wave * 16 + quad * 4) * 1024;

    float m_st[4], l_st[4];
    f32x4 o_acc[4];
    #pragma unroll
    for (int r = 0; r < 4; r++) { m_st[r] = -1e30f; l_st[r] = 0.0f; }
    #pragma unroll
    for (int j = 0; j < 4; j++)
        #pragma unroll
        for (int r = 0; r < 4; r++) o_acc[j][r] = 0.0f;

    // prefetch tile 0
    short8 pk0 = *(const short8*)(Kg);
    short8 pk1 = *(const short8*)(Kg + 8);
    short8 pv0 = *(const short8*)(Vg);
    short8 pv1 = *(const short8*)(Vg + 8);

    for (int kt = 0; kt < 16; kt++) {
        if (kt > 0) __syncthreads();            // prev compute done before overwrite
        *(short8*)(Ks + srow * 72 + scol)     = pk0;
        *(short8*)(Ks + srow * 72 + scol + 8) = pk1;
        *(short8*)(VT + srow * 72 + scol)     = pv0;
        *(short8*)(VT + srow * 72 + scol + 8) = pv1;
        __syncthreads();

        if (kt + 1 < 16) {                      // prefetch next tile (in flight over compute)
            pk0 = *(const short8*)(Kg + (kt + 1) * 4096);
            pk1 = *(const short8*)(Kg + (kt + 1) * 4096 + 8);
            pv0 = *(const short8*)(Vg + (kt + 1) * 64);
            pv1 = *(const short8*)(Vg + (kt + 1) * 64 + 8);
        }

        // rid gather: issue before QK^T so L2 latency hides under MFMA
        int rv[4][4];
        #pragma unroll
        for (int r = 0; r < 4; r++) {
            const int* rp = ridBase + (size_t)r * 1024 + kt * 64 + ml;
            #pragma unroll
            for (int j = 0; j < 4; j++) rv[r][j] = rp[j * 16];
        }

        // QK^T
        f32x4 s_acc[4];
        #pragma unroll
        for (int j = 0; j < 4; j++)
            #pragma unroll
            for (int r = 0; r < 4; r++) s_acc[j][r] = 0.0f;
        __builtin_amdgcn_s_setprio(1);
        #pragma unroll
        for (int j = 0; j < 4; j++) {
            short8 bk0 = *(const short8*)(Ks + (j * 16 + ml) * 72 + quad * 8);
            short8 bk1 = *(const short8*)(Ks + (j * 16 + ml) * 72 + 32 + quad * 8);
            s_acc[j] = __builtin_amdgcn_mfma_f32_16x16x32_bf16(aq0, bk0, s_acc[j], 0, 0, 0);
            s_acc[j] = __builtin_amdgcn_mfma_f32_16x16x32_bf16(aq1, bk1, s_acc[j], 0, 0, 0);
        }
        __builtin_amdgcn_s_setprio(0);

        // rel score add + LANE-LOCAL row max
        float mxl[4];
        #pragma unroll
        for (int r = 0; r < 4; r++) {
            int rl = quad * 4 + r;
            #pragma unroll
            for (int j = 0; j < 4; j++)
                s_acc[j][r] = s_acc[j][r] * scale + combS[wave][rl * 33 + rv[r][j]];
            mxl[r] = fmaxf(fmaxf(s_acc[0][r], s_acc[1][r]), fmaxf(s_acc[2][r], s_acc[3][r]));
        }

        // defer-max: all(lane_max <= m+8)  <=>  row_max <= m+8
        bool ok = (mxl[0] <= m_st[0] + 8.0f) & (mxl[1] <= m_st[1] + 8.0f)
                & (mxl[2] <= m_st[2] + 8.0f) & (mxl[3] <= m_st[3] + 8.0f);
        if (__all(ok)) {
            // common path: no shuffles, no rescale
            #pragma unroll
            for (int r = 0; r < 4; r++) {
                int rl = quad * 4 + r;
                float ps = 0.0f;
                #pragma unroll
                for (int j = 0; j < 4; j++) {
                    float pv = __expf(s_acc[j][r] - m_st[r]);
                    ps += pv;
                    Ps[wave][rl * 72 + j * 16 + ml] = f2bf(pv);
                }
                l_st[r] += ps;          // lane-local partial
            }
        } else {
            #pragma unroll
            for (int r = 0; r < 4; r++) {
                int rl = quad * 4 + r;
                float m0 = mxl[r];
                m0 = fmaxf(m0, __shfl_xor(m0, 1, 64));
                m0 = fmaxf(m0, __shfl_xor(m0, 2, 64));
                m0 = fmaxf(m0, __shfl_xor(m0, 4, 64));
                m0 = fmaxf(m0, __shfl_xor(m0, 8, 64));
                float mnew = fmaxf(m_st[r], m0);
                float alpha = __expf(m_st[r] - mnew);   // row-uniform
                float ps = 0.0f;
                #pragma unroll
                for (int j = 0; j < 4; j++) {
                    float pv = __expf(s_acc[j][r] - mnew);
                    ps += pv;
                    Ps[wave][rl * 72 + j * 16 + ml] = f2bf(pv);
                }
                l_st[r] = l_st[r] * alpha + ps;         // lane-local partial
                m_st[r] = mnew;
                #pragma unroll
                for (int j = 0; j < 4; j++) o_acc[j][r] *= alpha;
            }
        }

        // P.V: A from per-wave Ps, B from VT (both LDS)
        short8 ap0 = *(const short8*)(&Ps[wave][ml * 72 + quad * 8]);
        short8 ap1 = *(const short8*)(&Ps[wave][ml * 72 + 32 + quad * 8]);
        __builtin_amdgcn_s_setprio(1);
        #pragma unroll
        for (int j = 0; j < 4; j++) {
            short8 bv0 = *(const short8*)(VT + (j * 16 + ml) * 72 + quad * 8);
            short8 bv1 = *(const short8*)(VT + (j * 16 + ml) * 72 + 32 + quad * 8);
            o_acc[j] = __builtin_amdgcn_mfma_f32_16x16x32_bf16(ap0, bv0, o_acc[j], 0, 0, 0);
            o_acc[j] = __builtin_amdgcn_mfma_f32_16x16x32_bf16(ap1, bv1, o_acc[j], 0, 0, 0);
        }
        __builtin_amdgcn_s_setprio(0);
    }

    // epilogue: reduce lane-local l partials across the 16 lanes of each row
    #pragma unroll
    for (int r = 0; r < 4; r++) {
        float lr = l_st[r];
        lr += __shfl_xor(lr, 1, 64);
        lr += __shfl_xor(lr, 2, 64);
        lr += __shfl_xor(lr, 4, 64);
        lr += __shfl_xor(lr, 8, 64);
        int qrow = wave * 16 + quad * 4 + r;
        float invl = 1.0f / lr;
        size_t base = ((size_t)(b * 1024 + q0 + qrow)) * 1024 + h * 64;
        #pragma unroll
        for (int j = 0; j < 4; j++)
            outp[base + j * 16 + ml] = f2bf(o_acc[j][r] * invl);
    }
}

// ---------------------------------------------------------------------------
// LayerNorm( a + p0 [+ p1 [+ p2 [+ p3]]] ) * g + be  -> fp32 out (+ bf16 out).
// D = 1024. NP = number of partial buffers summed onto a.
// In-place safe: each thread reads its own 4 elements before writing them.
// ---------------------------------------------------------------------------
template <int NP>
__global__ __launch_bounds__(256) void ln_kernel(
    const float* __restrict__ a,
    const float* __restrict__ p0, const float* __restrict__ p1,
    const float* __restrict__ p2, const float* __restrict__ p3,
    const float* __restrict__ g, const float* __restrict__ be,
    float* __restrict__ outF, unsigned short* __restrict__ outB)
{
    int row = blockIdx.x, tid = threadIdx.x;
    int wave = tid >> 6, lane = tid & 63;
    size_t off = (size_t)row * 1024 + tid * 4;
    f32x4 x = *(const f32x4*)(a + off);
    {
        f32x4 t = *(const f32x4*)(p0 + off);
        #pragma unroll
        for (int i = 0; i < 4; i++) x[i] += t[i];
    }
    if (NP > 1) {
        f32x4 t = *(const f32x4*)(p1 + off);
        #pragma unroll
        for (int i = 0; i < 4; i++) x[i] += t[i];
    }
    if (NP > 2) {
        f32x4 t = *(const f32x4*)(p2 + off);
        #pragma unroll
        for (int i = 0; i < 4; i++) x[i] += t[i];
    }
    if (NP > 3) {
        f32x4 t = *(const f32x4*)(p3 + off);
        #pragma unroll
        for (int i = 0; i < 4; i++) x[i] += t[i];
    }
    float s1 = x[0] + x[1] + x[2] + x[3];
    float s2 = x[0]*x[0] + x[1]*x[1] + x[2]*x[2] + x[3]*x[3];
    #pragma unroll
    for (int offx = 1; offx < 64; offx <<= 1) {
        s1 += __shfl_xor(s1, offx, 64);
        s2 += __shfl_xor(s2, offx, 64);
    }
    __shared__ float r1[4], r2[4];
    if (lane == 0) { r1[wave] = s1; r2[wave] = s2; }
    __syncthreads();
    s1 = r1[0] + r1[1] + r1[2] + r1[3];
    s2 = r2[0] + r2[1] + r2[2] + r2[3];
    float mean = s1 * (1.0f / 1024.0f);
    float var  = s2 * (1.0f / 1024.0f) - mean * mean;
    float inv  = rsqrtf(var + 1e-6f);
    f32x4 gg = *(const f32x4*)(g + tid * 4);
    f32x4 bb = *(const f32x4*)(be + tid * 4);
    f32x4 o;
    #pragma unroll
    for (int i = 0; i < 4; i++) o[i] = (x[i] - mean) * inv * gg[i] + bb[i];
    *(f32x4*)(outF + off) = o;
    if (outB != nullptr) {
        ushort4v ov = { f2bf(o[0]), f2bf(o[1]), f2bf(o[2]), f2bf(o[3]) };
        *(ushort4v*)(outB + off) = ov;
    }
}

// ---------------------------------------------------------------------------
extern "C" void kernel_launch(void* const* d_in, const int* in_sizes, int n_in,
                              void* d_out, int out_size, void* d_ws, size_t ws_size,
                              hipStream_t stream)
{
    const float* x_in = (const float*)d_in[0];
    const int*   rid  = (const int*)d_in[1];
    const float* Wq = (const float*)d_in[2];  const float* bq = (const float*)d_in[3];
    const float* Wk = (const float*)d_in[4];  const float* bk = (const float*)d_in[5];
    const float* Wv = (const float*)d_in[6];  const float* bv = (const float*)d_in[7];
    const float* Wo = (const float*)d_in[8];  const float* bo = (const float*)d_in[9];
    const float* Erel = (const float*)d_in[10];
    const float* Brel = (const float*)d_in[11];
    const float* g1 = (const float*)d_in[12]; const float* be1 = (const float*)d_in[13];
    const float* g2 = (const float*)d_in[14]; const float* be2 = (const float*)d_in[15];
    const float* W1 = (const float*)d_in[16]; const float* b1 = (const float*)d_in[17];
    const float* W2 = (const float*)d_in[18]; const float* b2 = (const float*)d_in[19];

    char* p = (char*)d_ws;
    auto alloc = [&](size_t bytes) {
        char* r = p; p += (bytes + 255) & ~(size_t)255; return (void*)r;
    };
    unsigned short* wqkv_t = (unsigned short*)alloc(3ull * 1024 * 1024 * 2); // [3072][1024]
    unsigned short* wo_t   = (unsigned short*)alloc(1024ull * 1024 * 2);
    unsigned short* w1_t   = (unsigned short*)alloc(4096ull * 1024 * 2);
    unsigned short* w2_t   = (unsigned short*)alloc(1024ull * 4096 * 2);
    float*          xf     = (float*)alloc(4096ull * 1024 * 4);
    unsigned short* xb     = (unsigned short*)alloc(4096ull * 1024 * 2);
    unsigned short* qkvb   = (unsigned short*)alloc(3ull * 4194304 * 2);     // q|k|v
    unsigned short* vtb    = (unsigned short*)alloc(4194304ull * 2);         // V^T [B,H,64,S]
    unsigned short* attnb  = (unsigned short*)alloc(4096ull * 1024 * 2);
    float*          qEcb   = (float*)alloc(2162688ull * 4);                  // [B,H,S,33]
    float*          proj   = (float*)alloc(4096ull * 1024 * 4);
    float*          ffin   = (float*)alloc(4096ull * 1024 * 4);
    unsigned short* ffinb  = (unsigned short*)alloc(4096ull * 1024 * 2);
    unsigned short* hb     = qkvb;   // 32MB reuse (qkvb dead by FFN1; spans into vtb)

    // Split-K partial buffers, all reusing dead regions at their point of use:
    //  O-proj (z=2):  P0 = proj, P1 = ffin            (ffin dead until LN1 writes it)
    //  FFN2   (z=4):  P0 = proj, P1 = xf              (residual already consumed by LN1)
    //                 P2 = attnb∪qEcb (17.0 MB contig, both consumed)
    //                 P3 = wqkv_t∪wo_t∪w1_t (exactly 16.78 MB contig, weights consumed;
    //                      rewritten only at next layer's transpose, after LN2)
    float* pP2 = (float*)attnb;
    float* pP3 = (float*)wqkv_t;

    cvt_f32_bf16<<<4096, 256, 0, stream>>>(x_in, xb, 4194304);

    const float* xcur = x_in;
    for (int l = 0; l < 6; l++) {
        transpose_cvt<<<dim3(16, 16), 256, 0, stream>>>(Wq + (size_t)l * 1048576, wqkv_t,           1024, 1024);
        transpose_cvt<<<dim3(16, 16), 256, 0, stream>>>(Wk + (size_t)l * 1048576, wqkv_t + 1048576, 1024, 1024);
        transpose_cvt<<<dim3(16, 16), 256, 0, stream>>>(Wv + (size_t)l * 1048576, wqkv_t + 2097152, 1024, 1024);
        transpose_cvt<<<dim3(16, 16), 256, 0, stream>>>(Wo + (size_t)l * 1048576, wo_t,             1024, 1024);
        transpose_cvt<<<dim3(64, 16), 256, 0, stream>>>(W1 + (size_t)l * 4194304, w1_t, 1024, 4096);
        transpose_cvt<<<dim3(16, 64), 256, 0, stream>>>(W2 + (size_t)l * 4194304, w2_t, 4096, 1024);

        // QKV fused: [4096,1024] @ [1024,3072] -> q,k,v [B,H,S,64]
        gemm_bt<2><<<dim3(24, 32, 1), 256, 0, stream>>>(
            xb, wqkv_t, bq + l * 1024, bk + l * 1024, bv + l * 1024,
            nullptr, nullptr, nullptr, nullptr, qkvb, 4096, 3072, 1024, 1024);

        transpose_v<<<dim3(16, 64), 256, 0, stream>>>(qkvb + 8388608, vtb);

        qe_kernel<<<512, 256, 0, stream>>>(qkvb, Erel + l * 2112, Brel + l * 528, qEcb);

        attn_kernel<<<1024, 256, 0, stream>>>(
            qkvb, qkvb + 4194304, vtb, rid, qEcb, attnb);

        // O projection, split-K x2 -> partials proj, ffin
        gemm_bt<0><<<dim3(8, 32, 2), 256, 0, stream>>>(
            attnb, wo_t, bo + l * 1024, nullptr, nullptr,
            proj, ffin, nullptr, nullptr, nullptr, 4096, 1024, 1024, 512);

        // ff_in = LN(x + proj + ffin)   (writes ffin in-place: per-thread safe)
        ln_kernel<2><<<4096, 256, 0, stream>>>(
            xcur, proj, ffin, nullptr, nullptr,
            g1 + l * 1024, be1 + l * 1024, ffin, ffinb);

        // FFN1: relu(ffin @ W1 + b1) -> bf16 hb
        gemm_bt<1><<<dim3(32, 32, 1), 256, 0, stream>>>(
            ffinb, w1_t, b1 + l * 4096, nullptr, nullptr,
            nullptr, nullptr, nullptr, nullptr, hb, 4096, 4096, 1024, 1024);

        // FFN2: hb @ W2 + b2, split-K x4 -> partials proj, xf, attnb-region, wqkv-region
        gemm_bt<0><<<dim3(8, 32, 4), 256, 0, stream>>>(
            hb, w2_t, b2 + l * 1024, nullptr, nullptr,
            proj, xf, pP2, pP3, nullptr, 4096, 1024, 4096, 1024);

        // x_next = LN(ffin + sum of 4 partials)
        float* lnout = (l == 5) ? (float*)d_out : xf;
        unsigned short* lnoutb = (l == 5) ? nullptr : xb;
        ln_kernel<4><<<4096, 256, 0, stream>>>(
            ffin, proj, xf, pP2, pP3,
            g2 + l * 1024, be2 + l * 1024, lnout, lnoutb);
        xcur = xf;
    }
}